// Round 1
// baseline (611.621 us; speedup 1.0000x reference)
//
#include <hip/hip_runtime.h>
#include <cstdint>
#include <cstddef>

// ---------------------------------------------------------------------------
// Fused GQA MHA: B=2 S=2048 D=2048, G=4 HPG=4 DH=128 (16 heads)
// Pipeline: fp32->bf16 convert | NT-GEMM (Q,K,V proj) | flash attn | NT-GEMM (O)
// ---------------------------------------------------------------------------

typedef __attribute__((ext_vector_type(8))) __bf16 bf16x8;
typedef __attribute__((ext_vector_type(4))) float f32x4;

// async global->LDS, 16B per lane, linear LDS dest (wave-uniform base + lane*16)
#define GLD16(gp, lp) __builtin_amdgcn_global_load_lds(                         \
    (__attribute__((address_space(1))) void*)(size_t)(gp),                     \
    (__attribute__((address_space(3))) void*)(lp), 16, 0, 0)

// ---------------------------------------------------------------------------
// fp32 -> bf16 elementwise convert (vectorized 8/thread)
// ---------------------------------------------------------------------------
__global__ void f2b_kernel(const float* __restrict__ in, __bf16* __restrict__ out, long n8) {
    long stride = (long)gridDim.x * blockDim.x;
    for (long i = (long)blockIdx.x * blockDim.x + threadIdx.x; i < n8; i += stride) {
        const float4* p = (const float4*)(in + i * 8);
        float4 a = p[0], b = p[1];
        bf16x8 r;
        r[0] = (__bf16)a.x; r[1] = (__bf16)a.y; r[2] = (__bf16)a.z; r[3] = (__bf16)a.w;
        r[4] = (__bf16)b.x; r[5] = (__bf16)b.y; r[6] = (__bf16)b.z; r[7] = (__bf16)b.w;
        *(bf16x8*)(out + i * 8) = r;
    }
}

// ---------------------------------------------------------------------------
// NT GEMM: C[M,N] = A[M,K] * B[N,K]^T + bias[N]
// 128x128 tile, BK=32, 4 waves (2x2), each wave 64x64 (4x4 of 16x16x32 mfma)
// double-buffered LDS staged via global_load_lds width=16 (m97 structure)
// ---------------------------------------------------------------------------
template <int OUTF32>
__global__ __launch_bounds__(256)
void gemm_nt(const __bf16* __restrict__ A, const __bf16* __restrict__ Bm,
             const float* __restrict__ bias, float* __restrict__ Cf,
             __bf16* __restrict__ Cb, int M, int N, int K) {
    __shared__ __bf16 As[2][128 * 32];
    __shared__ __bf16 Bs[2][128 * 32];
    const int tid = threadIdx.x;
    const int lane = tid & 63, wid = tid >> 6;
    const int g = lane >> 4, c = lane & 15;
    const int m0 = blockIdx.x * 128, n0 = blockIdx.y * 128;
    const int wr = wid >> 1, wc = wid & 1;

    const f32x4 z = {0.f, 0.f, 0.f, 0.f};
    f32x4 acc[4][4];
#pragma unroll
    for (int i = 0; i < 4; ++i)
#pragma unroll
        for (int j = 0; j < 4; ++j) acc[i][j] = z;

    const int nk = K >> 5;
    // prologue: stage k-tile 0 into buffer 0
#pragma unroll
    for (int i = 0; i < 2; ++i) {
        int ci = i * 256 + tid, row = ci >> 2, kc = (ci & 3) * 8;
        GLD16(A + (size_t)(m0 + row) * K + kc, &As[0][ci * 8]);
        GLD16(Bm + (size_t)(n0 + row) * K + kc, &Bs[0][ci * 8]);
    }
    __syncthreads();

    int cur = 0;
    for (int t = 0; t < nk; ++t) {
        if (t + 1 < nk) {  // prefetch next k-tile into other buffer
            int koff = (t + 1) * 32;
#pragma unroll
            for (int i = 0; i < 2; ++i) {
                int ci = i * 256 + tid, row = ci >> 2, kc = (ci & 3) * 8;
                GLD16(A + (size_t)(m0 + row) * K + koff + kc, &As[cur ^ 1][ci * 8]);
                GLD16(Bm + (size_t)(n0 + row) * K + koff + kc, &Bs[cur ^ 1][ci * 8]);
            }
        }
        bf16x8 af[4], bfv[4];
#pragma unroll
        for (int im = 0; im < 4; ++im)
            af[im] = *(const bf16x8*)&As[cur][(wr * 64 + im * 16 + c) * 32 + g * 8];
#pragma unroll
        for (int in = 0; in < 4; ++in)
            bfv[in] = *(const bf16x8*)&Bs[cur][(wc * 64 + in * 16 + c) * 32 + g * 8];
#pragma unroll
        for (int im = 0; im < 4; ++im)
#pragma unroll
            for (int in = 0; in < 4; ++in)
                acc[im][in] = __builtin_amdgcn_mfma_f32_16x16x32_bf16(
                    af[im], bfv[in], acc[im][in], 0, 0, 0);
        __syncthreads();  // drains vmcnt for global_load_lds + lds reuse fence
        cur ^= 1;
    }

    // epilogue: C/D layout col=lane&15, row=(lane>>4)*4+r  [m89]
#pragma unroll
    for (int im = 0; im < 4; ++im) {
#pragma unroll
        for (int in = 0; in < 4; ++in) {
            int col = n0 + wc * 64 + in * 16 + c;
            float bv = bias[col];
#pragma unroll
            for (int r = 0; r < 4; ++r) {
                int row = m0 + wr * 64 + im * 16 + g * 4 + r;
                float v = acc[im][in][r] + bv;
                if (OUTF32) Cf[(size_t)row * N + col] = v;
                else        Cb[(size_t)row * N + col] = (__bf16)v;
            }
        }
    }
}

// ---------------------------------------------------------------------------
// Flash attention: one block = 64 q-rows of one head. 4 waves x 16 q-rows.
// K tiles (64x128) via global_load_lds with XOR chunk swizzle (pre-swizzled src);
// V staged transposed [128][64+8] (pad 8 keeps 16B alignment, ~4-way reads);
// P redistributed via per-wave LDS [16][72].
// ---------------------------------------------------------------------------
__global__ __launch_bounds__(256)
void attn_kernel(const __bf16* __restrict__ Qw, const __bf16* __restrict__ Kw,
                 const __bf16* __restrict__ Vw, __bf16* __restrict__ Ow) {
    constexpr int S = 2048, DQ = 2048, DKV = 512;
    const int qblk = blockIdx.x, head = blockIdx.y, b = blockIdx.z;
    const int grp = head >> 2;
    const __bf16* Q  = Qw + (size_t)b * S * DQ + head * 128;
    const __bf16* Kp = Kw + (size_t)b * S * DKV + grp * 128;
    const __bf16* Vp = Vw + (size_t)b * S * DKV + grp * 128;
    __bf16* Op = Ow + (size_t)b * S * DQ + head * 128;

    __shared__ __bf16 Ks[2][64 * 128];   // 32 KB (double buffered)
    __shared__ __bf16 Vt[128 * 72];      // 18 KB transposed V, pad 64->72
    __shared__ __bf16 Pl[4][16 * 72];    // 9 KB per-wave P staging, pad 64->72

    const int tid = threadIdx.x, wid = tid >> 6, lane = tid & 63;
    const int g = lane >> 4, c = lane & 15;
    const int qrow0 = qblk * 64 + wid * 16;

    // Q fragments in registers: A-operand row = lane&15
    bf16x8 qf[4];
#pragma unroll
    for (int ks = 0; ks < 4; ++ks)
        qf[ks] = *(const bf16x8*)(Q + (size_t)(qrow0 + c) * DQ + ks * 32 + g * 8);

    const f32x4 z = {0.f, 0.f, 0.f, 0.f};
    f32x4 o[8];
#pragma unroll
    for (int fn = 0; fn < 8; ++fn) o[fn] = z;
    float mprev[4] = {-1e30f, -1e30f, -1e30f, -1e30f};
    float lsum[4]  = {0.f, 0.f, 0.f, 0.f};

    // K stage: LDS chunk (key, ccl) holds global chunk (key, ccl ^ (key&15))
    auto stageK = [&](int buf, int t) {
#pragma unroll
        for (int i = 0; i < 4; ++i) {
            int ci = i * 256 + tid;
            int key = ci >> 4, ccl = ci & 15;
            int ccg = ccl ^ (key & 15);
            GLD16(Kp + (size_t)(t * 64 + key) * DKV + ccg * 8, &Ks[buf][ci * 8]);
        }
    };
    auto loadV = [&](bf16x8* dst, int t) {
#pragma unroll
        for (int i = 0; i < 4; ++i) {
            int ci = i * 256 + tid;
            int key = ci >> 4, dh0 = (ci & 15) * 8;
            dst[i] = *(const bf16x8*)(Vp + (size_t)(t * 64 + key) * DKV + dh0);
        }
    };
    auto writeVt = [&](const bf16x8* src) {
#pragma unroll
        for (int i = 0; i < 4; ++i) {
            int ci = i * 256 + tid;
            int key = ci >> 4, dh0 = (ci & 15) * 8;
#pragma unroll
            for (int j = 0; j < 8; ++j) Vt[(dh0 + j) * 72 + key] = src[i][j];
        }
    };

    bf16x8 vr[4], vrn[4];
    stageK(0, 0);
    loadV(vr, 0);
    __syncthreads();     // K0 staged (vmcnt drained)
    writeVt(vr);
    __syncthreads();     // Vt(0) visible

    const float scale = 0.08838834764831845f;  // 1/sqrt(128)
    const int nt = S / 64;
    int cur = 0;
    for (int t = 0; t < nt; ++t) {
        const bool pf = (t + 1) < nt;
        if (pf) { stageK(cur ^ 1, t + 1); loadV(vrn, t + 1); }

        // ---- QK^T: sc[jn] = Q(16x128) * K(64x128)^T quadrant jn
        f32x4 sc[4];
#pragma unroll
        for (int jn = 0; jn < 4; ++jn) {
            sc[jn] = z;
#pragma unroll
            for (int ks = 0; ks < 4; ++ks) {
                int key_l = jn * 16 + c;
                int ccl = (ks * 4 + g) ^ c;  // read-side swizzle (same involution)
                bf16x8 kf = *(const bf16x8*)&Ks[cur][key_l * 128 + ccl * 8];
                sc[jn] = __builtin_amdgcn_mfma_f32_16x16x32_bf16(qf[ks], kf, sc[jn], 0, 0, 0);
            }
        }

        // ---- online softmax (rows r spread over reg idx; 16 c-lanes share a row)
        float p[4][4], ef[4];
#pragma unroll
        for (int r = 0; r < 4; ++r) {
            float mx = fmaxf(fmaxf(sc[0][r], sc[1][r]), fmaxf(sc[2][r], sc[3][r])) * scale;
#pragma unroll
            for (int msk = 1; msk < 16; msk <<= 1) mx = fmaxf(mx, __shfl_xor(mx, msk, 64));
            float mn = fmaxf(mprev[r], mx);
            ef[r] = __expf(mprev[r] - mn);
            float rs = 0.f;
#pragma unroll
            for (int jn = 0; jn < 4; ++jn) {
                p[jn][r] = __expf(sc[jn][r] * scale - mn);
                rs += p[jn][r];
            }
#pragma unroll
            for (int msk = 1; msk < 16; msk <<= 1) rs += __shfl_xor(rs, msk, 64);
            lsum[r] = lsum[r] * ef[r] + rs;
            mprev[r] = mn;
        }
#pragma unroll
        for (int fn = 0; fn < 8; ++fn) {
            f32x4 e = {ef[0], ef[1], ef[2], ef[3]};
            o[fn] *= e;
        }

        // ---- P -> LDS (scores layout) then re-read as MFMA A-operand layout
#pragma unroll
        for (int jn = 0; jn < 4; ++jn)
#pragma unroll
            for (int r = 0; r < 4; ++r)
                Pl[wid][(g * 4 + r) * 72 + jn * 16 + c] = (__bf16)p[jn][r];
        asm volatile("" ::: "memory");  // keep program order (same-wave LDS is in-order)
        bf16x8 pfr[2];
#pragma unroll
        for (int k2 = 0; k2 < 2; ++k2)
            pfr[k2] = *(const bf16x8*)&Pl[wid][c * 72 + k2 * 32 + g * 8];

        // ---- PV: o += P(16x64) * V(64x128); Vt gives contiguous-in-key B frags
#pragma unroll
        for (int fn = 0; fn < 8; ++fn) {
#pragma unroll
            for (int k2 = 0; k2 < 2; ++k2) {
                bf16x8 vf = *(const bf16x8*)&Vt[(fn * 16 + c) * 72 + k2 * 32 + g * 8];
                o[fn] = __builtin_amdgcn_mfma_f32_16x16x32_bf16(pfr[k2], vf, o[fn], 0, 0, 0);
            }
        }
        __syncthreads();            // all reads of Vt / Ks[cur] done; K[cur^1] landed
        if (pf) writeVt(vrn);       // overwrite Vt with tile t+1
        __syncthreads();            // Vt(t+1) visible
        cur ^= 1;
    }

    // ---- epilogue: normalize and store
#pragma unroll
    for (int r = 0; r < 4; ++r) {
        float inv = 1.0f / lsum[r];
#pragma unroll
        for (int fn = 0; fn < 8; ++fn)
            Op[(size_t)(qrow0 + g * 4 + r) * DQ + fn * 16 + c] = (__bf16)(o[fn][r] * inv);
    }
}

// ---------------------------------------------------------------------------
extern "C" void kernel_launch(void* const* d_in, const int* in_sizes, int n_in,
                              void* d_out, int out_size, void* d_ws, size_t ws_size,
                              hipStream_t stream) {
    (void)in_sizes; (void)n_in; (void)out_size; (void)ws_size;
    const float* query = (const float*)d_in[0];
    const float* key   = (const float*)d_in[1];
    const float* value = (const float*)d_in[2];
    const float* WQ = (const float*)d_in[3];
    const float* bQ = (const float*)d_in[4];
    const float* WK = (const float*)d_in[5];
    const float* bK = (const float*)d_in[6];
    const float* WV = (const float*)d_in[7];
    const float* bV = (const float*)d_in[8];
    const float* WO = (const float*)d_in[9];
    const float* bO = (const float*)d_in[10];
    float* out = (float*)d_out;

    // workspace carve (bf16), total ~108 MB
    __bf16* w = (__bf16*)d_ws;
    __bf16* qb  = w; w += (size_t)4096 * 2048;  // query bf16
    __bf16* kb  = w; w += (size_t)4096 * 2048;  // key bf16
    __bf16* vb  = w; w += (size_t)4096 * 2048;  // value bf16
    __bf16* wqb = w; w += (size_t)2048 * 2048;  // WQ bf16 [2048,2048] rows=(g,h,dh)
    __bf16* wkb = w; w += (size_t)512 * 2048;   // WK bf16 [512,2048] rows=(g,dh)
    __bf16* wvb = w; w += (size_t)512 * 2048;   // WV bf16
    __bf16* wob = w; w += (size_t)2048 * 2048;  // WO bf16 [2048,2048]
    __bf16* qp  = w; w += (size_t)4096 * 2048;  // Q proj [B*S, 16*128]
    __bf16* kp  = w; w += (size_t)4096 * 512;   // K proj [B*S, 4*128]
    __bf16* vp  = w; w += (size_t)4096 * 512;   // V proj
    __bf16* ao  = w; w += (size_t)4096 * 2048;  // attention output [B*S, 2048]

    auto conv = [&](const float* src, __bf16* dst, long n) {
        long n8 = n >> 3;
        long blocks = (n8 + 255) / 256;
        if (blocks > 2048) blocks = 2048;
        f2b_kernel<<<(int)blocks, 256, 0, stream>>>(src, dst, n8);
    };
    conv(query, qb, (long)4096 * 2048);
    conv(key,   kb, (long)4096 * 2048);
    conv(value, vb, (long)4096 * 2048);
    conv(WQ, wqb, (long)2048 * 2048);
    conv(WK, wkb, (long)512 * 2048);
    conv(WV, wvb, (long)512 * 2048);
    conv(WO, wob, (long)2048 * 2048);

    // projections: NT GEMMs (weights are [N,K] row-major), bias epilogue, bf16 out
    gemm_nt<0><<<dim3(32, 16), 256, 0, stream>>>(qb, wqb, bQ, nullptr, qp, 4096, 2048, 2048);
    gemm_nt<0><<<dim3(32, 4),  256, 0, stream>>>(kb, wkb, bK, nullptr, kp, 4096, 512, 2048);
    gemm_nt<0><<<dim3(32, 4),  256, 0, stream>>>(vb, wvb, bV, nullptr, vp, 4096, 512, 2048);

    // flash attention: grid (q-tiles, heads, batch)
    attn_kernel<<<dim3(32, 16, 2), 256, 0, stream>>>(qp, kp, vp, ao);

    // output projection: fp32 out
    gemm_nt<1><<<dim3(32, 16), 256, 0, stream>>>(ao, wob, bO, out, nullptr, 4096, 2048, 2048);
}

// Round 2
// 384.049 us; speedup vs baseline: 1.5926x; 1.5926x over previous
//
#include <hip/hip_runtime.h>
#include <cstdint>
#include <cstddef>

// ---------------------------------------------------------------------------
// Fused GQA MHA: B=2 S=2048 D=2048, G=4 HPG=4 DH=128 (16 heads)
// fp32->bf16 convert | NT-GEMM (Q,K proj; V proj emits V^T) | flash attn | O proj
// ---------------------------------------------------------------------------

typedef __attribute__((ext_vector_type(8))) __bf16 bf16x8;
typedef __attribute__((ext_vector_type(4))) float f32x4;

// async global->LDS, 16B per lane, linear LDS dest (wave-uniform base + lane*16)
#define GLD16(gp, lp) __builtin_amdgcn_global_load_lds(                         \
    (__attribute__((address_space(1))) void*)(size_t)(gp),                     \
    (__attribute__((address_space(3))) void*)(lp), 16, 0, 0)

// ---------------------------------------------------------------------------
__global__ void f2b_kernel(const float* __restrict__ in, __bf16* __restrict__ out, long n8) {
    long stride = (long)gridDim.x * blockDim.x;
    for (long i = (long)blockIdx.x * blockDim.x + threadIdx.x; i < n8; i += stride) {
        const float4* p = (const float4*)(in + i * 8);
        float4 a = p[0], b = p[1];
        bf16x8 r;
        r[0] = (__bf16)a.x; r[1] = (__bf16)a.y; r[2] = (__bf16)a.z; r[3] = (__bf16)a.w;
        r[4] = (__bf16)b.x; r[5] = (__bf16)b.y; r[6] = (__bf16)b.z; r[7] = (__bf16)b.w;
        *(bf16x8*)(out + i * 8) = r;
    }
}

// ---------------------------------------------------------------------------
// NT GEMM: C[M,N] = A[M,K] * B[N,K]^T + bias   (bias per col, or per row)
// 128x128 tile, BK=32, 4 waves (2x2), m97 structure
// ---------------------------------------------------------------------------
template <int OUTF32, int BIASROW>
__global__ __launch_bounds__(256)
void gemm_nt(const __bf16* __restrict__ A, const __bf16* __restrict__ Bm,
             const float* __restrict__ bias, float* __restrict__ Cf,
             __bf16* __restrict__ Cb, int M, int N, int K) {
    __shared__ __bf16 As[2][128 * 32];
    __shared__ __bf16 Bs[2][128 * 32];
    const int tid = threadIdx.x;
    const int lane = tid & 63, wid = tid >> 6;
    const int g = lane >> 4, c = lane & 15;
    const int m0 = blockIdx.x * 128, n0 = blockIdx.y * 128;
    const int wr = wid >> 1, wc = wid & 1;

    const f32x4 z = {0.f, 0.f, 0.f, 0.f};
    f32x4 acc[4][4];
#pragma unroll
    for (int i = 0; i < 4; ++i)
#pragma unroll
        for (int j = 0; j < 4; ++j) acc[i][j] = z;

    const int nk = K >> 5;
#pragma unroll
    for (int i = 0; i < 2; ++i) {
        int ci = i * 256 + tid, row = ci >> 2, kc = (ci & 3) * 8;
        GLD16(A + (size_t)(m0 + row) * K + kc, &As[0][ci * 8]);
        GLD16(Bm + (size_t)(n0 + row) * K + kc, &Bs[0][ci * 8]);
    }
    __syncthreads();

    int cur = 0;
    for (int t = 0; t < nk; ++t) {
        if (t + 1 < nk) {
            int koff = (t + 1) * 32;
#pragma unroll
            for (int i = 0; i < 2; ++i) {
                int ci = i * 256 + tid, row = ci >> 2, kc = (ci & 3) * 8;
                GLD16(A + (size_t)(m0 + row) * K + koff + kc, &As[cur ^ 1][ci * 8]);
                GLD16(Bm + (size_t)(n0 + row) * K + koff + kc, &Bs[cur ^ 1][ci * 8]);
            }
        }
        bf16x8 af[4], bfv[4];
#pragma unroll
        for (int im = 0; im < 4; ++im)
            af[im] = *(const bf16x8*)&As[cur][(wr * 64 + im * 16 + c) * 32 + g * 8];
#pragma unroll
        for (int in = 0; in < 4; ++in)
            bfv[in] = *(const bf16x8*)&Bs[cur][(wc * 64 + in * 16 + c) * 32 + g * 8];
        __builtin_amdgcn_s_setprio(1);
#pragma unroll
        for (int im = 0; im < 4; ++im)
#pragma unroll
            for (int in = 0; in < 4; ++in)
                acc[im][in] = __builtin_amdgcn_mfma_f32_16x16x32_bf16(
                    af[im], bfv[in], acc[im][in], 0, 0, 0);
        __builtin_amdgcn_s_setprio(0);
        __syncthreads();
        cur ^= 1;
    }

    // epilogue: C/D layout col=lane&15, row=(lane>>4)*4+r  [m89]
#pragma unroll
    for (int im = 0; im < 4; ++im) {
#pragma unroll
        for (int in = 0; in < 4; ++in) {
            int col = n0 + wc * 64 + in * 16 + c;
            float bvc = BIASROW ? 0.f : bias[col];
#pragma unroll
            for (int r = 0; r < 4; ++r) {
                int row = m0 + wr * 64 + im * 16 + g * 4 + r;
                float v = acc[im][in][r] + (BIASROW ? bias[row] : bvc);
                if (OUTF32) Cf[(size_t)row * N + col] = v;
                else        Cb[(size_t)row * N + col] = (__bf16)v;
            }
        }
    }
}

// ---------------------------------------------------------------------------
// Flash attention. One block = 64 q-rows of one head; 4 waves x 16 q-rows.
// K  tile [64 keys][128 dh]  : GLD16, 16-chunk XOR swizzle (chunk ^= key&15)
// V^T tile [128 dh][64 keys] : GLD16, 8-chunk  XOR swizzle (chunk ^= dh&7)
// P  staging per-wave [16 q][64 keys], 8-chunk XOR swizzle (chunk ^= q&7)
// One __syncthreads per tile (double-buffered K and V^T).
// ---------------------------------------------------------------------------
__global__ __launch_bounds__(256)
void attn_kernel(const __bf16* __restrict__ Qw, const __bf16* __restrict__ Kw,
                 const __bf16* __restrict__ VTw, __bf16* __restrict__ Ow) {
    constexpr int S = 2048, DQ = 2048, DKV = 512, TOK = 4096;
    const int qblk = blockIdx.x, head = blockIdx.y, b = blockIdx.z;
    const int grp = head >> 2;
    const __bf16* Q   = Qw + (size_t)b * S * DQ + head * 128;
    const __bf16* Kp  = Kw + (size_t)b * S * DKV + grp * 128;
    const __bf16* VTp = VTw + (size_t)(grp * 128) * TOK + (size_t)b * S;
    __bf16* Op = Ow + (size_t)b * S * DQ + head * 128;

    __shared__ __bf16 Ks[2][64 * 128];   // 32 KB
    __shared__ __bf16 Vs[2][128 * 64];   // 32 KB (V^T, key-contiguous rows)
    __shared__ __bf16 Pl[4][16 * 64];    // 8 KB per-wave P staging

    const int tid = threadIdx.x, wid = tid >> 6, lane = tid & 63;
    const int g = lane >> 4, c = lane & 15;
    const int qrow0 = qblk * 64 + wid * 16;

    bf16x8 qf[4];
#pragma unroll
    for (int ks = 0; ks < 4; ++ks)
        qf[ks] = *(const bf16x8*)(Q + (size_t)(qrow0 + c) * DQ + ks * 32 + g * 8);

    const f32x4 z = {0.f, 0.f, 0.f, 0.f};
    f32x4 o[8];
#pragma unroll
    for (int fn = 0; fn < 8; ++fn) o[fn] = z;
    float mprev[4] = {-1e30f, -1e30f, -1e30f, -1e30f};
    float lsum[4]  = {0.f, 0.f, 0.f, 0.f};

    auto stage = [&](int buf, int t) {
#pragma unroll
        for (int i = 0; i < 4; ++i) {           // K: [key][dh], swizzle dh-chunks
            int ci = i * 256 + tid;
            int key = ci >> 4, ccl = ci & 15, ccg = ccl ^ (key & 15);
            GLD16(Kp + (size_t)(t * 64 + key) * DKV + ccg * 8, &Ks[buf][ci * 8]);
        }
#pragma unroll
        for (int i = 0; i < 4; ++i) {           // V^T: [dh][key], swizzle key-chunks
            int ci = i * 256 + tid;
            int dh = ci >> 3, cl = ci & 7, cg = cl ^ (dh & 7);
            GLD16(VTp + (size_t)dh * TOK + t * 64 + cg * 8, &Vs[buf][ci * 8]);
        }
    };

    stage(0, 0);
    __syncthreads();

    const float scale = 0.08838834764831845f;  // 1/sqrt(128)
    const int nt = S / 64;
    int cur = 0;
    for (int t = 0; t < nt; ++t) {
        if (t + 1 < nt) stage(cur ^ 1, t + 1);

        // ---- QK^T: sc[jn] = Q(16x128) * K(64x128)^T quadrant jn
        f32x4 sc[4];
        __builtin_amdgcn_s_setprio(1);
#pragma unroll
        for (int jn = 0; jn < 4; ++jn) {
            sc[jn] = z;
#pragma unroll
            for (int ks = 0; ks < 4; ++ks) {
                int ccl = (ks * 4 + g) ^ c;   // read-side involution
                bf16x8 kf = *(const bf16x8*)&Ks[cur][(jn * 16 + c) * 128 + ccl * 8];
                sc[jn] = __builtin_amdgcn_mfma_f32_16x16x32_bf16(qf[ks], kf, sc[jn], 0, 0, 0);
            }
        }
        __builtin_amdgcn_s_setprio(0);

        // ---- online softmax (row q = g*4+r across reg idx; 16 c-lanes share row)
        float p[4][4], ef[4];
#pragma unroll
        for (int r = 0; r < 4; ++r) {
            float mx = fmaxf(fmaxf(sc[0][r], sc[1][r]), fmaxf(sc[2][r], sc[3][r])) * scale;
#pragma unroll
            for (int msk = 1; msk < 16; msk <<= 1) mx = fmaxf(mx, __shfl_xor(mx, msk, 64));
            float mn = fmaxf(mprev[r], mx);
            ef[r] = __expf(mprev[r] - mn);
            float rs = 0.f;
#pragma unroll
            for (int jn = 0; jn < 4; ++jn) {
                p[jn][r] = __expf(sc[jn][r] * scale - mn);
                rs += p[jn][r];
            }
#pragma unroll
            for (int msk = 1; msk < 16; msk <<= 1) rs += __shfl_xor(rs, msk, 64);
            lsum[r] = lsum[r] * ef[r] + rs;
            mprev[r] = mn;
        }
#pragma unroll
        for (int fn = 0; fn < 8; ++fn) {
            f32x4 e = {ef[0], ef[1], ef[2], ef[3]};
            o[fn] *= e;
        }

        // ---- P -> per-wave LDS (swizzled) then re-read as MFMA A-fragments
#pragma unroll
        for (int jn = 0; jn < 4; ++jn)
#pragma unroll
            for (int r = 0; r < 4; ++r) {
                int q = g * 4 + r;
                int chg = jn * 2 + (c >> 3);          // global key-chunk
                int chl = chg ^ (q & 7);              // swizzled
                Pl[wid][q * 64 + chl * 8 + (c & 7)] = (__bf16)p[jn][r];
            }
        asm volatile("" ::: "memory");
        bf16x8 pfr[2];
#pragma unroll
        for (int k2 = 0; k2 < 2; ++k2)
            pfr[k2] = *(const bf16x8*)&Pl[wid][c * 64 + (((k2 * 4 + g) ^ (c & 7)) * 8)];

        // ---- PV: o += P(16x64) * V(64x128), B-frags from swizzled V^T rows
        __builtin_amdgcn_s_setprio(1);
#pragma unroll
        for (int fn = 0; fn < 8; ++fn) {
#pragma unroll
            for (int k2 = 0; k2 < 2; ++k2) {
                int chl = (k2 * 4 + g) ^ (c & 7);     // read-side involution
                bf16x8 vf = *(const bf16x8*)&Vs[cur][(fn * 16 + c) * 64 + chl * 8];
                o[fn] = __builtin_amdgcn_mfma_f32_16x16x32_bf16(pfr[k2], vf, o[fn], 0, 0, 0);
            }
        }
        __builtin_amdgcn_s_setprio(0);
        __syncthreads();   // drains vmcnt (stage t+1 done) + all reads of cur done
        cur ^= 1;
    }

    // ---- epilogue
#pragma unroll
    for (int r = 0; r < 4; ++r) {
        float inv = 1.0f / lsum[r];
#pragma unroll
        for (int fn = 0; fn < 8; ++fn)
            Op[(size_t)(qrow0 + g * 4 + r) * DQ + fn * 16 + c] = (__bf16)(o[fn][r] * inv);
    }
}

// ---------------------------------------------------------------------------
extern "C" void kernel_launch(void* const* d_in, const int* in_sizes, int n_in,
                              void* d_out, int out_size, void* d_ws, size_t ws_size,
                              hipStream_t stream) {
    (void)in_sizes; (void)n_in; (void)out_size; (void)ws_size;
    const float* query = (const float*)d_in[0];
    const float* key   = (const float*)d_in[1];
    const float* value = (const float*)d_in[2];
    const float* WQ = (const float*)d_in[3];
    const float* bQ = (const float*)d_in[4];
    const float* WK = (const float*)d_in[5];
    const float* bK = (const float*)d_in[6];
    const float* WV = (const float*)d_in[7];
    const float* bV = (const float*)d_in[8];
    const float* WO = (const float*)d_in[9];
    const float* bO = (const float*)d_in[10];
    float* out = (float*)d_out;

    __bf16* w = (__bf16*)d_ws;
    __bf16* qb  = w; w += (size_t)4096 * 2048;  // query bf16
    __bf16* kb  = w; w += (size_t)4096 * 2048;  // key bf16
    __bf16* vb  = w; w += (size_t)4096 * 2048;  // value bf16
    __bf16* wqb = w; w += (size_t)2048 * 2048;  // WQ bf16 rows=(g,h,dh)
    __bf16* wkb = w; w += (size_t)512 * 2048;   // WK bf16 rows=(g,dh)
    __bf16* wvb = w; w += (size_t)512 * 2048;   // WV bf16
    __bf16* wob = w; w += (size_t)2048 * 2048;  // WO bf16
    __bf16* qp  = w; w += (size_t)4096 * 2048;  // Q proj [tok, 16*128]
    __bf16* kp  = w; w += (size_t)4096 * 512;   // K proj [tok, 4*128]
    __bf16* vpT = w; w += (size_t)512 * 4096;   // V proj TRANSPOSED [4*128, tok]
    __bf16* ao  = w; w += (size_t)4096 * 2048;  // attention output [tok, 2048]

    auto conv = [&](const float* src, __bf16* dst, long n) {
        long n8 = n >> 3;
        long blocks = (n8 + 255) / 256;
        if (blocks > 2048) blocks = 2048;
        f2b_kernel<<<(int)blocks, 256, 0, stream>>>(src, dst, n8);
    };
    conv(query, qb, (long)4096 * 2048);
    conv(key,   kb, (long)4096 * 2048);
    conv(value, vb, (long)4096 * 2048);
    conv(WQ, wqb, (long)2048 * 2048);
    conv(WK, wkb, (long)512 * 2048);
    conv(WV, wvb, (long)512 * 2048);
    conv(WO, wob, (long)2048 * 2048);

    // Q, K projections (bias per col). V projection with swapped roles:
    // C[dh_flat, tok] = WV[dh_flat,:] . value[tok,:]  -> V^T directly (bias per row)
    gemm_nt<0,0><<<dim3(32, 16), 256, 0, stream>>>(qb, wqb, bQ, nullptr, qp, 4096, 2048, 2048);
    gemm_nt<0,0><<<dim3(32, 4),  256, 0, stream>>>(kb, wkb, bK, nullptr, kp, 4096, 512, 2048);
    gemm_nt<0,1><<<dim3(4, 32),  256, 0, stream>>>(wvb, vb, bV, nullptr, vpT, 512, 4096, 2048);

    attn_kernel<<<dim3(32, 16, 2), 256, 0, stream>>>(qp, kp, vpT, ao);

    gemm_nt<1,0><<<dim3(32, 16), 256, 0, stream>>>(ao, wob, bO, out, nullptr, 4096, 2048, 2048);
}

// Round 4
// 353.827 us; speedup vs baseline: 1.7286x; 1.0854x over previous
//
#include <hip/hip_runtime.h>
#include <cstdint>
#include <cstddef>

// ---------------------------------------------------------------------------
// Fused GQA MHA: B=2 S=2048 D=2048, G=4 HPG=4 DH=128 (16 heads)
// fp32->bf16 convert | NT-GEMM (Q,K proj; V proj emits V^T) | flash attn | O proj
// ---------------------------------------------------------------------------

typedef __attribute__((ext_vector_type(8)))  __bf16 bf16x8;
typedef __attribute__((ext_vector_type(4)))  __bf16 bf16x4;
typedef __attribute__((ext_vector_type(4)))  float  f32x4;
typedef __attribute__((ext_vector_type(16))) float  f32x16;
typedef __attribute__((ext_vector_type(4)))  unsigned int u32x4;

#define GLD16(gp, lp) __builtin_amdgcn_global_load_lds(                         \
    (__attribute__((address_space(1))) void*)(size_t)(gp),                     \
    (__attribute__((address_space(3))) void*)(lp), 16, 0, 0)

// v_permlane32_swap: a' = {a.lanes0-31, b.lanes0-31}, b' = {a.lanes32-63, b.lanes32-63}
#define PLSWAP(a, b) asm volatile("v_permlane32_swap_b32 %0, %1" : "+v"(a), "+v"(b))

#define EXP2F(x) __builtin_amdgcn_exp2f(x)

static __device__ __forceinline__ unsigned pack2bf(float a, float b) {
    unsigned short ua = __builtin_bit_cast(unsigned short, (__bf16)a);
    unsigned short ub = __builtin_bit_cast(unsigned short, (__bf16)b);
    return (unsigned)ua | ((unsigned)ub << 16);
}

// ---------------------------------------------------------------------------
__global__ void f2b_kernel(const float* __restrict__ in, __bf16* __restrict__ out, long n8) {
    long stride = (long)gridDim.x * blockDim.x;
    for (long i = (long)blockIdx.x * blockDim.x + threadIdx.x; i < n8; i += stride) {
        const float4* p = (const float4*)(in + i * 8);
        float4 a = p[0], b = p[1];
        bf16x8 r;
        r[0] = (__bf16)a.x; r[1] = (__bf16)a.y; r[2] = (__bf16)a.z; r[3] = (__bf16)a.w;
        r[4] = (__bf16)b.x; r[5] = (__bf16)b.y; r[6] = (__bf16)b.z; r[7] = (__bf16)b.w;
        *(bf16x8*)(out + i * 8) = r;
    }
}

// ---------------------------------------------------------------------------
// NT GEMM: C[M,N] = A[M,K] * B[N,K]^T + bias  (m97 structure)
// ---------------------------------------------------------------------------
template <int OUTF32, int BIASROW>
__global__ __launch_bounds__(256)
void gemm_nt(const __bf16* __restrict__ A, const __bf16* __restrict__ Bm,
             const float* __restrict__ bias, float* __restrict__ Cf,
             __bf16* __restrict__ Cb, int M, int N, int K) {
    __shared__ __bf16 As[2][128 * 32];
    __shared__ __bf16 Bs[2][128 * 32];
    const int tid = threadIdx.x;
    const int lane = tid & 63, wid = tid >> 6;
    const int g = lane >> 4, c = lane & 15;
    const int m0 = blockIdx.x * 128, n0 = blockIdx.y * 128;
    const int wr = wid >> 1, wc = wid & 1;

    const f32x4 z = {0.f, 0.f, 0.f, 0.f};
    f32x4 acc[4][4];
#pragma unroll
    for (int i = 0; i < 4; ++i)
#pragma unroll
        for (int j = 0; j < 4; ++j) acc[i][j] = z;

    const int nk = K >> 5;
#pragma unroll
    for (int i = 0; i < 2; ++i) {
        int ci = i * 256 + tid, row = ci >> 2, kc = (ci & 3) * 8;
        GLD16(A + (size_t)(m0 + row) * K + kc, &As[0][ci * 8]);
        GLD16(Bm + (size_t)(n0 + row) * K + kc, &Bs[0][ci * 8]);
    }
    __syncthreads();

    int cur = 0;
    for (int t = 0; t < nk; ++t) {
        if (t + 1 < nk) {
            int koff = (t + 1) * 32;
#pragma unroll
            for (int i = 0; i < 2; ++i) {
                int ci = i * 256 + tid, row = ci >> 2, kc = (ci & 3) * 8;
                GLD16(A + (size_t)(m0 + row) * K + koff + kc, &As[cur ^ 1][ci * 8]);
                GLD16(Bm + (size_t)(n0 + row) * K + koff + kc, &Bs[cur ^ 1][ci * 8]);
            }
        }
        bf16x8 af[4], bfv[4];
#pragma unroll
        for (int im = 0; im < 4; ++im)
            af[im] = *(const bf16x8*)&As[cur][(wr * 64 + im * 16 + c) * 32 + g * 8];
#pragma unroll
        for (int in = 0; in < 4; ++in)
            bfv[in] = *(const bf16x8*)&Bs[cur][(wc * 64 + in * 16 + c) * 32 + g * 8];
        __builtin_amdgcn_s_setprio(1);
#pragma unroll
        for (int im = 0; im < 4; ++im)
#pragma unroll
            for (int in = 0; in < 4; ++in)
                acc[im][in] = __builtin_amdgcn_mfma_f32_16x16x32_bf16(
                    af[im], bfv[in], acc[im][in], 0, 0, 0);
        __builtin_amdgcn_s_setprio(0);
        __syncthreads();
        cur ^= 1;
    }

#pragma unroll
    for (int im = 0; im < 4; ++im) {
#pragma unroll
        for (int in = 0; in < 4; ++in) {
            int col = n0 + wc * 64 + in * 16 + c;
            float bvc = BIASROW ? 0.f : bias[col];
#pragma unroll
            for (int r = 0; r < 4; ++r) {
                int row = m0 + wr * 64 + im * 16 + g * 4 + r;
                float v = acc[im][in][r] + (BIASROW ? bias[row] : bvc);
                if (OUTF32) Cf[(size_t)row * N + col] = v;
                else        Cb[(size_t)row * N + col] = (__bf16)v;
            }
        }
    }
}

// ---------------------------------------------------------------------------
// Flash attention, 32x32x16 swapped-operand structure.
// Block = 128 q-rows of one head, 4 waves x 32 q. Lane owns q = lane&31.
//   QK^T: sc[kt] = mfma(K-frag, Q-frag) -> D[key][q]   (K from LDS, Q in regs)
//   softmax: in-register, one shfl_xor(32) per reduce
//   P: bf16-pack + v_permlane32_swap -> B-fragments (no LDS)
//   PV:  o[dht]  = mfma(VT-frag, P-frag) -> D[dh][q]   (V^T from LDS)
// K swizzle: chunk ^= key&15. V^T swizzle: chunk ^= (dh^(dh>>3))&7.
// ---------------------------------------------------------------------------
__global__ __launch_bounds__(256)
void attn_kernel(const __bf16* __restrict__ Qw, const __bf16* __restrict__ Kw,
                 const __bf16* __restrict__ VTw, __bf16* __restrict__ Ow) {
    constexpr int S = 2048, DQ = 2048, DKV = 512, TOK = 4096;
    const int qblk = blockIdx.x, head = blockIdx.y, b = blockIdx.z;
    const int grp = head >> 2;
    const __bf16* Q   = Qw + (size_t)b * S * DQ + head * 128;
    const __bf16* Kp  = Kw + (size_t)b * S * DKV + grp * 128;
    const __bf16* VTp = VTw + (size_t)(grp * 128) * TOK + (size_t)b * S;
    __bf16* Op = Ow + (size_t)b * S * DQ + head * 128;

    __shared__ __bf16 Ks[2][64 * 128];   // 32 KB
    __shared__ __bf16 Vs[2][128 * 64];   // 32 KB (V^T rows key-contiguous)

    const int tid = threadIdx.x, wid = tid >> 6, lane = tid & 63;
    const int ql = lane & 31, hi = lane >> 5;
    const int qrow = qblk * 128 + wid * 32 + ql;

    // Q as B-operand fragments: col=lane&31=q, k=(lane>>5)*8+j
    bf16x8 qf[8];
#pragma unroll
    for (int ks = 0; ks < 8; ++ks)
        qf[ks] = *(const bf16x8*)(Q + (size_t)qrow * DQ + ks * 16 + hi * 8);

    f32x16 o[4];
#pragma unroll
    for (int d = 0; d < 4; ++d)
#pragma unroll
        for (int r = 0; r < 16; ++r) o[d][r] = 0.f;
    float mprev = -1e30f, lsum = 0.f;
    constexpr float kexp = 0.08838834764831845f * 1.4426950408889634f; // log2e/sqrt(128)

    auto stage = [&](int buf, int t) {
#pragma unroll
        for (int i = 0; i < 4; ++i) {            // K [key][dh-chunk^key&15]
            int ci = i * 256 + tid;
            int key = ci >> 4, ccl = ci & 15, ccg = ccl ^ (key & 15);
            GLD16(Kp + (size_t)(t * 64 + key) * DKV + ccg * 8, &Ks[buf][ci * 8]);
        }
#pragma unroll
        for (int i = 0; i < 4; ++i) {            // V^T [dh][key-chunk^s(dh)]
            int ci = i * 256 + tid;
            int dh = ci >> 3, cl = ci & 7, cg = cl ^ ((dh ^ (dh >> 3)) & 7);
            GLD16(VTp + (size_t)dh * TOK + t * 64 + cg * 8, &Vs[buf][ci * 8]);
        }
    };

    stage(0, 0);
    __syncthreads();

    const int nt = S / 64;
    int cur = 0;
    for (int t = 0; t < nt; ++t) {
        if (t + 1 < nt) stage(cur ^ 1, t + 1);

        // ---- QK^T: sc[kt] = K(32x128) x Q^T(128x32), kt = key half-tile
        f32x16 sc[2];
        __builtin_amdgcn_s_setprio(1);
#pragma unroll
        for (int kt = 0; kt < 2; ++kt) {
#pragma unroll
            for (int r = 0; r < 16; ++r) sc[kt][r] = 0.f;
#pragma unroll
            for (int ks = 0; ks < 8; ++ks) {
                int key = kt * 32 + ql;
                int chl = (ks * 2 + hi) ^ (key & 15);
                bf16x8 kf = *(const bf16x8*)&Ks[cur][key * 128 + chl * 8];
                sc[kt] = __builtin_amdgcn_mfma_f32_32x32x16_bf16(kf, qf[ks], sc[kt], 0, 0, 0);
            }
        }
        __builtin_amdgcn_s_setprio(0);

        // ---- online softmax, lane-local (q = lane&31; keys split across hi)
        float mo = sc[0][0];
#pragma unroll
        for (int r = 1; r < 16; ++r) mo = fmaxf(mo, sc[0][r]);
#pragma unroll
        for (int r = 0; r < 16; ++r) mo = fmaxf(mo, sc[1][r]);
        mo = fmaxf(mo, __shfl_xor(mo, 32, 64));
        float mn = fmaxf(mprev, mo);
        float ef = EXP2F((mprev - mn) * kexp);
        float mnk = mn * kexp;
        float rs = 0.f;
#pragma unroll
        for (int kt = 0; kt < 2; ++kt)
#pragma unroll
            for (int r = 0; r < 16; ++r) {
                float p = EXP2F(__builtin_fmaf(sc[kt][r], kexp, -mnk));
                sc[kt][r] = p;
                rs += p;
            }
        rs += __shfl_xor(rs, 32, 64);
        lsum = lsum * ef + rs;
        mprev = mn;
#pragma unroll
        for (int d = 0; d < 4; ++d)
#pragma unroll
            for (int r = 0; r < 16; ++r) o[d][r] *= ef;

        // ---- pack P to bf16 pairs: pk[kt][rg] covers keys {0..3}+8rg+4hi+32kt
        unsigned pk[2][4][2];
#pragma unroll
        for (int kt = 0; kt < 2; ++kt)
#pragma unroll
            for (int rg = 0; rg < 4; ++rg) {
                pk[kt][rg][0] = pack2bf(sc[kt][rg * 4 + 0], sc[kt][rg * 4 + 1]);
                pk[kt][rg][1] = pack2bf(sc[kt][rg * 4 + 2], sc[kt][rg * 4 + 3]);
            }

        // ---- PV: o[dht] += V^T(32x16) x P(16x32) over 4 key-steps
        __builtin_amdgcn_s_setprio(1);
#pragma unroll
        for (int ks = 0; ks < 4; ++ks) {
            const int kt = ks >> 1, e = ks & 1;
            unsigned a0 = pk[kt][2 * e][0], b0 = pk[kt][2 * e + 1][0];
            unsigned a1 = pk[kt][2 * e][1], b1 = pk[kt][2 * e + 1][1];
            PLSWAP(a0, b0);
            PLSWAP(a1, b1);
            u32x4 fw = {a0, a1, b0, b1};
            bf16x8 pf = __builtin_bit_cast(bf16x8, fw);
#pragma unroll
            for (int dht = 0; dht < 4; ++dht) {
                int dh = dht * 32 + ql;
                int chl = (ks * 2 + hi) ^ ((dh ^ (dh >> 3)) & 7);
                bf16x8 vf = *(const bf16x8*)&Vs[cur][dh * 64 + chl * 8];
                o[dht] = __builtin_amdgcn_mfma_f32_32x32x16_bf16(vf, pf, o[dht], 0, 0, 0);
            }
        }
        __builtin_amdgcn_s_setprio(0);
        __syncthreads();   // drains vmcnt (stage t+1) + all reads of cur done
        cur ^= 1;
    }

    // ---- epilogue: o reg r of tile dht -> dh = dht*32 + 8*(r>>2) + 4*hi + (r&3)
    float inv = 1.0f / lsum;
#pragma unroll
    for (int dht = 0; dht < 4; ++dht)
#pragma unroll
        for (int rg = 0; rg < 4; ++rg) {
            bf16x4 wv;
#pragma unroll
            for (int j = 0; j < 4; ++j) wv[j] = (__bf16)(o[dht][rg * 4 + j] * inv);
            int dh0 = dht * 32 + rg * 8 + hi * 4;
            *(bf16x4*)(Op + (size_t)qrow * DQ + dh0) = wv;
        }
}

// ---------------------------------------------------------------------------
extern "C" void kernel_launch(void* const* d_in, const int* in_sizes, int n_in,
                              void* d_out, int out_size, void* d_ws, size_t ws_size,
                              hipStream_t stream) {
    (void)in_sizes; (void)n_in; (void)out_size; (void)ws_size;
    const float* query = (const float*)d_in[0];
    const float* key   = (const float*)d_in[1];
    const float* value = (const float*)d_in[2];
    const float* WQ = (const float*)d_in[3];
    const float* bQ = (const float*)d_in[4];
    const float* WK = (const float*)d_in[5];
    const float* bK = (const float*)d_in[6];
    const float* WV = (const float*)d_in[7];
    const float* bV = (const float*)d_in[8];
    const float* WO = (const float*)d_in[9];
    const float* bO = (const float*)d_in[10];
    float* out = (float*)d_out;

    __bf16* w = (__bf16*)d_ws;
    __bf16* qb  = w; w += (size_t)4096 * 2048;
    __bf16* kb  = w; w += (size_t)4096 * 2048;
    __bf16* vb  = w; w += (size_t)4096 * 2048;
    __bf16* wqb = w; w += (size_t)2048 * 2048;
    __bf16* wkb = w; w += (size_t)512 * 2048;
    __bf16* wvb = w; w += (size_t)512 * 2048;
    __bf16* wob = w; w += (size_t)2048 * 2048;
    __bf16* qp  = w; w += (size_t)4096 * 2048;  // Q proj [tok, 16*128]
    __bf16* kp  = w; w += (size_t)4096 * 512;   // K proj [tok, 4*128]
    __bf16* vpT = w; w += (size_t)512 * 4096;   // V proj transposed [4*128, tok]
    __bf16* ao  = w; w += (size_t)4096 * 2048;  // attention output

    auto conv = [&](const float* src, __bf16* dst, long n) {
        long n8 = n >> 3;
        long blocks = (n8 + 255) / 256;
        if (blocks > 2048) blocks = 2048;
        f2b_kernel<<<(int)blocks, 256, 0, stream>>>(src, dst, n8);
    };
    conv(query, qb, (long)4096 * 2048);
    conv(key,   kb, (long)4096 * 2048);
    conv(value, vb, (long)4096 * 2048);
    conv(WQ, wqb, (long)2048 * 2048);
    conv(WK, wkb, (long)512 * 2048);
    conv(WV, wvb, (long)512 * 2048);
    conv(WO, wob, (long)2048 * 2048);

    gemm_nt<0,0><<<dim3(32, 16), 256, 0, stream>>>(qb, wqb, bQ, nullptr, qp, 4096, 2048, 2048);
    gemm_nt<0,0><<<dim3(32, 4),  256, 0, stream>>>(kb, wkb, bK, nullptr, kp, 4096, 512, 2048);
    gemm_nt<0,1><<<dim3(4, 32),  256, 0, stream>>>(wvb, vb, bV, nullptr, vpT, 512, 4096, 2048);

    attn_kernel<<<dim3(16, 16, 2), 256, 0, stream>>>(qp, kp, vpT, ao);

    gemm_nt<1,0><<<dim3(32, 16), 256, 0, stream>>>(ao, wob, bO, out, nullptr, 4096, 2048, 2048);
}

// Round 5
// 314.542 us; speedup vs baseline: 1.9445x; 1.1249x over previous
//
#include <hip/hip_runtime.h>
#include <cstdint>
#include <cstddef>

// ---------------------------------------------------------------------------
// Fused GQA MHA: B=2 S=2048 D=2048, G=4 HPG=4 DH=128 (16 heads)
// fp32->bf16 convert | NT-GEMM (Q; K+V merged, V emits V^T) | flash attn | O proj
// ---------------------------------------------------------------------------

typedef __attribute__((ext_vector_type(8)))  __bf16 bf16x8;
typedef __attribute__((ext_vector_type(4)))  __bf16 bf16x4;
typedef __attribute__((ext_vector_type(4)))  float  f32x4;
typedef __attribute__((ext_vector_type(16))) float  f32x16;
typedef __attribute__((ext_vector_type(4)))  unsigned int u32x4;

#define GLD16(gp, lp) __builtin_amdgcn_global_load_lds(                         \
    (__attribute__((address_space(1))) void*)(size_t)(gp),                     \
    (__attribute__((address_space(3))) void*)(lp), 16, 0, 0)

// v_permlane32_swap: a' = {a.lanes0-31, b.lanes0-31}, b' = {a.lanes32-63, b.lanes32-63}
#define PLSWAP(a, b) asm volatile("v_permlane32_swap_b32 %0, %1" : "+v"(a), "+v"(b))

#define EXP2F(x) __builtin_amdgcn_exp2f(x)

static __device__ __forceinline__ unsigned pack2bf(float a, float b) {
    unsigned short ua = __builtin_bit_cast(unsigned short, (__bf16)a);
    unsigned short ub = __builtin_bit_cast(unsigned short, (__bf16)b);
    return (unsigned)ua | ((unsigned)ub << 16);
}

// ---------------------------------------------------------------------------
__global__ void f2b_kernel(const float* __restrict__ in, __bf16* __restrict__ out, long n8) {
    long stride = (long)gridDim.x * blockDim.x;
    for (long i = (long)blockIdx.x * blockDim.x + threadIdx.x; i < n8; i += stride) {
        const float4* p = (const float4*)(in + i * 8);
        float4 a = p[0], b = p[1];
        bf16x8 r;
        r[0] = (__bf16)a.x; r[1] = (__bf16)a.y; r[2] = (__bf16)a.z; r[3] = (__bf16)a.w;
        r[4] = (__bf16)b.x; r[5] = (__bf16)b.y; r[6] = (__bf16)b.z; r[7] = (__bf16)b.w;
        *(bf16x8*)(out + i * 8) = r;
    }
}

// ---------------------------------------------------------------------------
// NT GEMM tile body: C[M,N] = A[M,K]*B[N,K]^T + bias. 128x128 tile, BK=32,
// 4 waves (2x2), m97 structure. As/Bs are 2*128*32 double buffers.
// ---------------------------------------------------------------------------
template <int OUTF32>
static __device__ __forceinline__
void gemm_tile(const __bf16* __restrict__ A, const __bf16* __restrict__ Bm,
               const float* __restrict__ bias, float* __restrict__ Cf,
               __bf16* __restrict__ Cb, int N, int K, int m0, int n0, int biasrow,
               __bf16* As, __bf16* Bs) {
    const int tid = threadIdx.x;
    const int lane = tid & 63, wid = tid >> 6;
    const int g = lane >> 4, c = lane & 15;
    const int wr = wid >> 1, wc = wid & 1;

    const f32x4 z = {0.f, 0.f, 0.f, 0.f};
    f32x4 acc[4][4];
#pragma unroll
    for (int i = 0; i < 4; ++i)
#pragma unroll
        for (int j = 0; j < 4; ++j) acc[i][j] = z;

    const int nk = K >> 5;
#pragma unroll
    for (int i = 0; i < 2; ++i) {
        int ci = i * 256 + tid, row = ci >> 2, kc = (ci & 3) * 8;
        GLD16(A + (size_t)(m0 + row) * K + kc, As + ci * 8);
        GLD16(Bm + (size_t)(n0 + row) * K + kc, Bs + ci * 8);
    }
    __syncthreads();

    int cur = 0;
    for (int t = 0; t < nk; ++t) {
        if (t + 1 < nk) {
            int koff = (t + 1) * 32;
            int nb = (cur ^ 1) * 4096;
#pragma unroll
            for (int i = 0; i < 2; ++i) {
                int ci = i * 256 + tid, row = ci >> 2, kc = (ci & 3) * 8;
                GLD16(A + (size_t)(m0 + row) * K + koff + kc, As + nb + ci * 8);
                GLD16(Bm + (size_t)(n0 + row) * K + koff + kc, Bs + nb + ci * 8);
            }
        }
        int cb = cur * 4096;
        bf16x8 af[4], bfv[4];
#pragma unroll
        for (int im = 0; im < 4; ++im)
            af[im] = *(const bf16x8*)&As[cb + (wr * 64 + im * 16 + c) * 32 + g * 8];
#pragma unroll
        for (int in = 0; in < 4; ++in)
            bfv[in] = *(const bf16x8*)&Bs[cb + (wc * 64 + in * 16 + c) * 32 + g * 8];
        __builtin_amdgcn_s_setprio(1);
#pragma unroll
        for (int im = 0; im < 4; ++im)
#pragma unroll
            for (int in = 0; in < 4; ++in)
                acc[im][in] = __builtin_amdgcn_mfma_f32_16x16x32_bf16(
                    af[im], bfv[in], acc[im][in], 0, 0, 0);
        __builtin_amdgcn_s_setprio(0);
        __syncthreads();
        cur ^= 1;
    }

    // epilogue: C/D layout col=lane&15, row=(lane>>4)*4+r  [m89]
#pragma unroll
    for (int im = 0; im < 4; ++im) {
#pragma unroll
        for (int in = 0; in < 4; ++in) {
            int col = n0 + wc * 64 + in * 16 + c;
            float bvc = biasrow ? 0.f : bias[col];
#pragma unroll
            for (int r = 0; r < 4; ++r) {
                int row = m0 + wr * 64 + im * 16 + g * 4 + r;
                float v = acc[im][in][r] + (biasrow ? bias[row] : bvc);
                if (OUTF32) Cf[(size_t)row * N + col] = v;
                else        Cb[(size_t)row * N + col] = (__bf16)v;
            }
        }
    }
}

// Large GEMM with T1 XCD-aware swizzle (grid must be divisible by 8).
template <int OUTF32>
__global__ __launch_bounds__(256)
void gemm_main(const __bf16* __restrict__ A, const __bf16* __restrict__ Bm,
               const float* __restrict__ bias, float* __restrict__ Cf,
               __bf16* __restrict__ Cb, int N, int K, int nbx) {
    __shared__ __bf16 As[2 * 128 * 32];
    __shared__ __bf16 Bs[2 * 128 * 32];
    const int cpx = gridDim.x >> 3;
    const int bid = blockIdx.x;
    const int swz = (bid & 7) * cpx + (bid >> 3);
    const int bx = swz % nbx, by = swz / nbx;
    gemm_tile<OUTF32>(A, Bm, bias, Cf, Cb, N, K, bx * 128, by * 128, 0, As, Bs);
}

// K-proj (128 tiles) + V^T-proj (128 tiles) merged into one 256-block dispatch.
__global__ __launch_bounds__(256)
void gemm_kv(const __bf16* __restrict__ kb, const __bf16* __restrict__ wkb,
             const float* __restrict__ bK, __bf16* __restrict__ kp,
             const __bf16* __restrict__ wvb, const __bf16* __restrict__ vb,
             const float* __restrict__ bV, __bf16* __restrict__ vpT) {
    __shared__ __bf16 As[2 * 128 * 32];
    __shared__ __bf16 Bs[2 * 128 * 32];
    const int bid = blockIdx.x;
    const int swz = (bid & 7) * 32 + (bid >> 3);   // 256 blocks
    if (swz < 128) {
        // K proj: C[4096,512] = kb[4096,2048] x wkb[512,2048]^T (+bK per col)
        int bx = swz & 31, by = swz >> 5;
        gemm_tile<0>(kb, wkb, bK, nullptr, kp, 512, 2048, bx * 128, by * 128, 0, As, Bs);
    } else {
        // V^T proj: C[512,4096] = wvb[512,2048] x vb[4096,2048]^T (+bV per row)
        int s2 = swz - 128;
        int bx = s2 & 3, by = s2 >> 2;
        gemm_tile<0>(wvb, vb, bV, nullptr, vpT, 4096, 2048, bx * 128, by * 128, 1, As, Bs);
    }
}

// ---------------------------------------------------------------------------
// Flash attention, 32x32x16 swapped-operand structure + XCD-exact placement.
// 1-D grid of 512; bid&7 selects (b,grp) so each XCD's 64 blocks share one
// 1 MB K/V set (L2-resident). Block = 128 q-rows of one head, 4 waves x 32 q.
//   QK^T: sc[kt] = mfma(K-frag, Q-frag) -> D[key][q]
//   softmax: in-register, defer-max (T13, THR=8), one shfl_xor(32) per reduce
//   P: bf16-pack + v_permlane32_swap -> B-fragments (no LDS)
//   PV:  o[dht]  = mfma(VT-frag, P-frag) -> D[dh][q]
// K swizzle: chunk ^= key&15. V^T swizzle: chunk ^= (dh^(dh>>3))&7.
// ---------------------------------------------------------------------------
__global__ __launch_bounds__(256)
void attn_kernel(const __bf16* __restrict__ Qw, const __bf16* __restrict__ Kw,
                 const __bf16* __restrict__ VTw, __bf16* __restrict__ Ow) {
    constexpr int S = 2048, DQ = 2048, DKV = 512, TOK = 4096;
    const int bid = blockIdx.x;
    const int xcd = bid & 7, slot = bid >> 3;
    const int b = xcd >> 2, grp = xcd & 3;
    const int head = grp * 4 + (slot & 3);
    const int qblk = slot >> 2;                    // [0,16)
    const __bf16* Q   = Qw + (size_t)b * S * DQ + head * 128;
    const __bf16* Kp  = Kw + (size_t)b * S * DKV + grp * 128;
    const __bf16* VTp = VTw + (size_t)(grp * 128) * TOK + (size_t)b * S;
    __bf16* Op = Ow + (size_t)b * S * DQ + head * 128;

    __shared__ __bf16 Ks[2][64 * 128];   // 32 KB
    __shared__ __bf16 Vs[2][128 * 64];   // 32 KB (V^T rows key-contiguous)

    const int tid = threadIdx.x, wid = tid >> 6, lane = tid & 63;
    const int ql = lane & 31, hi = lane >> 5;
    const int qrow = qblk * 128 + wid * 32 + ql;

    // Q as B-operand fragments: col=lane&31=q, k=(lane>>5)*8+j
    bf16x8 qf[8];
#pragma unroll
    for (int ks = 0; ks < 8; ++ks)
        qf[ks] = *(const bf16x8*)(Q + (size_t)qrow * DQ + ks * 16 + hi * 8);

    f32x16 o[4];
#pragma unroll
    for (int d = 0; d < 4; ++d)
#pragma unroll
        for (int r = 0; r < 16; ++r) o[d][r] = 0.f;
    float mprev = -1e30f, lsum = 0.f;
    constexpr float kexp = 0.08838834764831845f * 1.4426950408889634f; // log2e/sqrt(128)
    constexpr float THR = 8.0f / kexp;   // defer-max threshold in raw-score units

    auto stage = [&](int buf, int t) {
#pragma unroll
        for (int i = 0; i < 4; ++i) {            // K [key][dh-chunk^key&15]
            int ci = i * 256 + tid;
            int key = ci >> 4, ccl = ci & 15, ccg = ccl ^ (key & 15);
            GLD16(Kp + (size_t)(t * 64 + key) * DKV + ccg * 8, &Ks[buf][ci * 8]);
        }
#pragma unroll
        for (int i = 0; i < 4; ++i) {            // V^T [dh][key-chunk^s(dh)]
            int ci = i * 256 + tid;
            int dh = ci >> 3, cl = ci & 7, cg = cl ^ ((dh ^ (dh >> 3)) & 7);
            GLD16(VTp + (size_t)dh * TOK + t * 64 + cg * 8, &Vs[buf][ci * 8]);
        }
    };

    stage(0, 0);
    __syncthreads();

    const int nt = S / 64;
    int cur = 0;
    for (int t = 0; t < nt; ++t) {
        if (t + 1 < nt) stage(cur ^ 1, t + 1);

        // ---- QK^T: sc[kt] = K(32x128) x Q^T(128x32), kt = key half-tile
        f32x16 sc[2];
        __builtin_amdgcn_s_setprio(1);
#pragma unroll
        for (int kt = 0; kt < 2; ++kt) {
#pragma unroll
            for (int r = 0; r < 16; ++r) sc[kt][r] = 0.f;
#pragma unroll
            for (int ks = 0; ks < 8; ++ks) {
                int key = kt * 32 + ql;
                int chl = (ks * 2 + hi) ^ (key & 15);
                bf16x8 kf = *(const bf16x8*)&Ks[cur][key * 128 + chl * 8];
                sc[kt] = __builtin_amdgcn_mfma_f32_32x32x16_bf16(kf, qf[ks], sc[kt], 0, 0, 0);
            }
        }
        __builtin_amdgcn_s_setprio(0);

        // ---- online softmax, lane-local (q = lane&31; keys split across hi)
        float mo = sc[0][0];
#pragma unroll
        for (int r = 1; r < 16; ++r) mo = fmaxf(mo, sc[0][r]);
#pragma unroll
        for (int r = 0; r < 16; ++r) mo = fmaxf(mo, sc[1][r]);
        mo = fmaxf(mo, __shfl_xor(mo, 32, 64));
        // T13 defer-max: rescale only when tile max exceeds running max by >THR
        if (!__all(mo - mprev <= THR)) {
            float mn = fmaxf(mprev, mo);
            float ef = EXP2F((mprev - mn) * kexp);
            lsum *= ef;
#pragma unroll
            for (int d = 0; d < 4; ++d)
#pragma unroll
                for (int r = 0; r < 16; ++r) o[d][r] *= ef;
            mprev = mn;
        }
        float mnk = mprev * kexp;
        float rs = 0.f;
#pragma unroll
        for (int kt = 0; kt < 2; ++kt)
#pragma unroll
            for (int r = 0; r < 16; ++r) {
                float p = EXP2F(__builtin_fmaf(sc[kt][r], kexp, -mnk));
                sc[kt][r] = p;
                rs += p;
            }
        rs += __shfl_xor(rs, 32, 64);
        lsum += rs;

        // ---- pack P to bf16 pairs: pk[kt][rg] covers keys {0..3}+8rg+4hi+32kt
        unsigned pk[2][4][2];
#pragma unroll
        for (int kt = 0; kt < 2; ++kt)
#pragma unroll
            for (int rg = 0; rg < 4; ++rg) {
                pk[kt][rg][0] = pack2bf(sc[kt][rg * 4 + 0], sc[kt][rg * 4 + 1]);
                pk[kt][rg][1] = pack2bf(sc[kt][rg * 4 + 2], sc[kt][rg * 4 + 3]);
            }

        // ---- PV: o[dht] += V^T(32x16) x P(16x32) over 4 key-steps
        __builtin_amdgcn_s_setprio(1);
#pragma unroll
        for (int ks = 0; ks < 4; ++ks) {
            const int kt = ks >> 1, e = ks & 1;
            unsigned a0 = pk[kt][2 * e][0], b0 = pk[kt][2 * e + 1][0];
            unsigned a1 = pk[kt][2 * e][1], b1 = pk[kt][2 * e + 1][1];
            PLSWAP(a0, b0);
            PLSWAP(a1, b1);
            u32x4 fw = {a0, a1, b0, b1};
            bf16x8 pf = __builtin_bit_cast(bf16x8, fw);
#pragma unroll
            for (int dht = 0; dht < 4; ++dht) {
                int dh = dht * 32 + ql;
                int chl = (ks * 2 + hi) ^ ((dh ^ (dh >> 3)) & 7);
                bf16x8 vf = *(const bf16x8*)&Vs[cur][dh * 64 + chl * 8];
                o[dht] = __builtin_amdgcn_mfma_f32_32x32x16_bf16(vf, pf, o[dht], 0, 0, 0);
            }
        }
        __builtin_amdgcn_s_setprio(0);
        __syncthreads();   // drains vmcnt (stage t+1) + all reads of cur done
        cur ^= 1;
    }

    // ---- epilogue: o reg r of tile dht -> dh = dht*32 + 8*(r>>2) + 4*hi + (r&3)
    float inv = 1.0f / lsum;
#pragma unroll
    for (int dht = 0; dht < 4; ++dht)
#pragma unroll
        for (int rg = 0; rg < 4; ++rg) {
            bf16x4 wv;
#pragma unroll
            for (int j = 0; j < 4; ++j) wv[j] = (__bf16)(o[dht][rg * 4 + j] * inv);
            int dh0 = dht * 32 + rg * 8 + hi * 4;
            *(bf16x4*)(Op + (size_t)qrow * DQ + dh0) = wv;
        }
}

// ---------------------------------------------------------------------------
extern "C" void kernel_launch(void* const* d_in, const int* in_sizes, int n_in,
                              void* d_out, int out_size, void* d_ws, size_t ws_size,
                              hipStream_t stream) {
    (void)in_sizes; (void)n_in; (void)out_size; (void)ws_size;
    const float* query = (const float*)d_in[0];
    const float* key   = (const float*)d_in[1];
    const float* value = (const float*)d_in[2];
    const float* WQ = (const float*)d_in[3];
    const float* bQ = (const float*)d_in[4];
    const float* WK = (const float*)d_in[5];
    const float* bK = (const float*)d_in[6];
    const float* WV = (const float*)d_in[7];
    const float* bV = (const float*)d_in[8];
    const float* WO = (const float*)d_in[9];
    const float* bO = (const float*)d_in[10];
    float* out = (float*)d_out;

    __bf16* w = (__bf16*)d_ws;
    __bf16* qb  = w; w += (size_t)4096 * 2048;
    __bf16* kb  = w; w += (size_t)4096 * 2048;
    __bf16* vb  = w; w += (size_t)4096 * 2048;
    __bf16* wqb = w; w += (size_t)2048 * 2048;
    __bf16* wkb = w; w += (size_t)512 * 2048;
    __bf16* wvb = w; w += (size_t)512 * 2048;
    __bf16* wob = w; w += (size_t)2048 * 2048;
    __bf16* qp  = w; w += (size_t)4096 * 2048;  // Q proj [tok, 16*128]
    __bf16* kp  = w; w += (size_t)4096 * 512;   // K proj [tok, 4*128]
    __bf16* vpT = w; w += (size_t)512 * 4096;   // V proj transposed [4*128, tok]
    __bf16* ao  = w; w += (size_t)4096 * 2048;  // attention output

    auto conv = [&](const float* src, __bf16* dst, long n) {
        long n8 = n >> 3;
        long blocks = (n8 + 255) / 256;
        if (blocks > 2048) blocks = 2048;
        f2b_kernel<<<(int)blocks, 256, 0, stream>>>(src, dst, n8);
    };
    conv(query, qb, (long)4096 * 2048);
    conv(key,   kb, (long)4096 * 2048);
    conv(value, vb, (long)4096 * 2048);
    conv(WQ, wqb, (long)2048 * 2048);
    conv(WK, wkb, (long)512 * 2048);
    conv(WV, wvb, (long)512 * 2048);
    conv(WO, wob, (long)2048 * 2048);

    // Q projection (512 tiles, T1 swizzle), K+V merged (256 tiles)
    gemm_main<0><<<512, 256, 0, stream>>>(qb, wqb, bQ, nullptr, qp, 2048, 2048, 32);
    gemm_kv<<<256, 256, 0, stream>>>(kb, wkb, bK, kp, wvb, vb, bV, vpT);

    // flash attention: 1-D grid, XCD-exact (b,grp) placement
    attn_kernel<<<512, 256, 0, stream>>>(qp, kp, vpT, ao);

    // output projection (fp32 out)
    gemm_main<1><<<512, 256, 0, stream>>>(ao, wob, bO, out, nullptr, 2048, 2048, 32);
}

// Round 6
// 292.846 us; speedup vs baseline: 2.0885x; 1.0741x over previous
//
#include <hip/hip_runtime.h>
#include <cstdint>
#include <cstddef>

// ---------------------------------------------------------------------------
// Fused GQA MHA: B=2 S=2048 D=2048, G=4 HPG=4 DH=128 (16 heads)
// fp32->bf16 convert | gemm256 (Q proj) + gemm_kv (K, V^T) | flash attn | O proj
// ---------------------------------------------------------------------------

typedef __attribute__((ext_vector_type(8)))  __bf16 bf16x8;
typedef __attribute__((ext_vector_type(4)))  __bf16 bf16x4;
typedef __attribute__((ext_vector_type(4)))  float  f32x4;
typedef __attribute__((ext_vector_type(16))) float  f32x16;
typedef __attribute__((ext_vector_type(4)))  unsigned int u32x4;

#define GLD16(gp, lp) __builtin_amdgcn_global_load_lds(                         \
    (__attribute__((address_space(1))) void*)(size_t)(gp),                     \
    (__attribute__((address_space(3))) void*)(lp), 16, 0, 0)

#define PLSWAP(a, b) asm volatile("v_permlane32_swap_b32 %0, %1" : "+v"(a), "+v"(b))
#define EXP2F(x) __builtin_amdgcn_exp2f(x)

static __device__ __forceinline__ unsigned pack2bf(float a, float b) {
    unsigned short ua = __builtin_bit_cast(unsigned short, (__bf16)a);
    unsigned short ub = __builtin_bit_cast(unsigned short, (__bf16)b);
    return (unsigned)ua | ((unsigned)ub << 16);
}

// ---------------------------------------------------------------------------
__global__ void f2b_kernel(const float* __restrict__ in, __bf16* __restrict__ out, long n8) {
    long stride = (long)gridDim.x * blockDim.x;
    for (long i = (long)blockIdx.x * blockDim.x + threadIdx.x; i < n8; i += stride) {
        const float4* p = (const float4*)(in + i * 8);
        float4 a = p[0], b = p[1];
        bf16x8 r;
        r[0] = (__bf16)a.x; r[1] = (__bf16)a.y; r[2] = (__bf16)a.z; r[3] = (__bf16)a.w;
        r[4] = (__bf16)b.x; r[5] = (__bf16)b.y; r[6] = (__bf16)b.z; r[7] = (__bf16)b.w;
        *(bf16x8*)(out + i * 8) = r;
    }
}

// ---------------------------------------------------------------------------
// gemm256: C[M,N] = A[M,K]*B[N,K]^T + bias[col]. BM=256 BN=128 BK=64, 8 waves
// (4m x 2n), 512 thr, triple-buffered LDS (144 KB), 2 phases/K-tile, counted
// vmcnt(6) across raw s_barrier (T3/T4), chunk-XOR LDS swizzle (T2, rule #21:
// inverse-swizzled GLD16 source + swizzled ds_read), T5 setprio. Grid: nbx*nby
// divisible by 8 (T1 bijective XCD swizzle).
// ---------------------------------------------------------------------------
template <int OUTF32>
__global__ __launch_bounds__(512)
void gemm256(const __bf16* __restrict__ A, const __bf16* __restrict__ Bm,
             const float* __restrict__ bias, float* __restrict__ Cf,
             __bf16* __restrict__ Cb, int M, int N, int K, int nbx) {
    __shared__ __bf16 As[3][256 * 64];   // 96 KB
    __shared__ __bf16 Bs[3][128 * 64];   // 48 KB
    const int tid = threadIdx.x, lane = tid & 63, wid = tid >> 6;
    const int g = lane >> 4, c = lane & 15;
    const int wr = wid >> 1, wc = wid & 1;           // 4m x 2n wave grid
    const int cpx = gridDim.x >> 3;
    const int swz = ((int)blockIdx.x & 7) * cpx + ((int)blockIdx.x >> 3);
    const int bx = swz % nbx, by = swz / nbx;
    const int m0 = by * 256, n0 = bx * 128;
    const int nkt = K >> 6;

    const f32x4 z = {0.f, 0.f, 0.f, 0.f};
    f32x4 acc[4][4];
#pragma unroll
    for (int i = 0; i < 4; ++i)
#pragma unroll
        for (int j = 0; j < 4; ++j) acc[i][j] = z;

    // stage A half h (rows h*128..h*128+127) of K-tile kt into buf b (2 GLD16)
    auto stageA = [&](int b, int kt, int h) {
        if (kt >= nkt) return;
        const __bf16* src = A + (size_t)m0 * K + (size_t)kt * 64;
#pragma unroll
        for (int i = 0; i < 2; ++i) {
            int ci = h * 1024 + i * 512 + tid;       // [0,2048)
            int row = ci >> 3, chg = (ci & 7) ^ (row & 7);
            GLD16(src + (size_t)row * K + chg * 8, &As[b][ci * 8]);
        }
    };
    auto stageB = [&](int b, int kt) {               // full 128-row B tile (2 GLD16)
        if (kt >= nkt) return;
        const __bf16* src = Bm + (size_t)n0 * K + (size_t)kt * 64;
#pragma unroll
        for (int i = 0; i < 2; ++i) {
            int ci = i * 512 + tid;                  // [0,1024)
            int row = ci >> 3, chg = (ci & 7) ^ (row & 7);
            GLD16(src + (size_t)row * K + chg * 8, &Bs[b][ci * 8]);
        }
    };

    // prologue: kt0 -> buf0, kt1 -> buf1 (6 loads each); wait kt0 landed
    stageA(0, 0, 0); stageA(0, 0, 1); stageB(0, 0);
    stageA(1, 1, 0); stageA(1, 1, 1); stageB(1, 1);
    asm volatile("s_waitcnt vmcnt(6)" ::: "memory");
    __builtin_amdgcn_sched_barrier(0);
    __builtin_amdgcn_s_barrier();

    int bd = 0;                                      // buf holding kt
    for (int kt = 0; kt < nkt; ++kt) {
        const int bs = (bd >= 1) ? bd - 1 : 2;       // buf for kt+2
        bf16x8 af[4], bfr[4];
#pragma unroll
        for (int ph = 0; ph < 2; ++ph) {             // ph = k-step (K=32 each)
            // ds-read fragments (swizzled chunks; row&7 == c&7)
#pragma unroll
            for (int mi = 0; mi < 4; ++mi) {
                int row = wr * 64 + mi * 16 + c;
                int ch = (ph * 4 + g) ^ (c & 7);
                af[mi] = *(const bf16x8*)&As[bd][row * 64 + ch * 8];
            }
#pragma unroll
            for (int ni = 0; ni < 4; ++ni) {
                int row = wc * 64 + ni * 16 + c;
                int ch = (ph * 4 + g) ^ (c & 7);
                bfr[ni] = *(const bf16x8*)&Bs[bd][row * 64 + ch * 8];
            }
            // issue prefetch of kt+2 (never waited this iter)
            if (ph == 0) {
                stageA(bs, kt + 2, 0);
            } else {
                stageA(bs, kt + 2, 1);
                stageB(bs, kt + 2);
            }
            __builtin_amdgcn_s_barrier();
            asm volatile("s_waitcnt lgkmcnt(0)" ::: "memory");
            __builtin_amdgcn_sched_barrier(0);       // rule #18: fence MFMA hoist
            __builtin_amdgcn_s_setprio(1);
#pragma unroll
            for (int mi = 0; mi < 4; ++mi)
#pragma unroll
                for (int ni = 0; ni < 4; ++ni)
                    acc[mi][ni] = __builtin_amdgcn_mfma_f32_16x16x32_bf16(
                        af[mi], bfr[ni], acc[mi][ni], 0, 0, 0);
            __builtin_amdgcn_s_setprio(0);
            if (ph == 1) {
                // K-tile boundary: kt+1 (staged during kt-1) must be landed;
                // kt+2's 6 loads stay in flight. Tail: full drain.
                if (kt >= nkt - 2) asm volatile("s_waitcnt vmcnt(0)" ::: "memory");
                else               asm volatile("s_waitcnt vmcnt(6)" ::: "memory");
                __builtin_amdgcn_sched_barrier(0);
            }
            __builtin_amdgcn_s_barrier();
        }
        bd = (bd >= 2) ? 0 : bd + 1;
    }

    // epilogue: C/D layout col=lane&15, row=(lane>>4)*4+r  [m89]
#pragma unroll
    for (int mi = 0; mi < 4; ++mi) {
#pragma unroll
        for (int ni = 0; ni < 4; ++ni) {
            int col = n0 + wc * 64 + ni * 16 + c;
            float bvc = bias[col];
#pragma unroll
            for (int r = 0; r < 4; ++r) {
                int row = m0 + wr * 64 + mi * 16 + g * 4 + r;
                float v = acc[mi][ni][r] + bvc;
                if (OUTF32) Cf[(size_t)row * N + col] = v;
                else        Cb[(size_t)row * N + col] = (__bf16)v;
            }
        }
    }
}

// ---------------------------------------------------------------------------
// m97-structure NT GEMM tile body (kept for the small K/V projections)
// ---------------------------------------------------------------------------
static __device__ __forceinline__
void gemm_tile(const __bf16* __restrict__ A, const __bf16* __restrict__ Bm,
               const float* __restrict__ bias,
               __bf16* __restrict__ Cb, int N, int K, int m0, int n0, int biasrow,
               __bf16* As, __bf16* Bs) {
    const int tid = threadIdx.x;
    const int lane = tid & 63, wid = tid >> 6;
    const int g = lane >> 4, c = lane & 15;
    const int wr = wid >> 1, wc = wid & 1;

    const f32x4 z = {0.f, 0.f, 0.f, 0.f};
    f32x4 acc[4][4];
#pragma unroll
    for (int i = 0; i < 4; ++i)
#pragma unroll
        for (int j = 0; j < 4; ++j) acc[i][j] = z;

    const int nk = K >> 5;
#pragma unroll
    for (int i = 0; i < 2; ++i) {
        int ci = i * 256 + tid, row = ci >> 2, kc = (ci & 3) * 8;
        GLD16(A + (size_t)(m0 + row) * K + kc, As + ci * 8);
        GLD16(Bm + (size_t)(n0 + row) * K + kc, Bs + ci * 8);
    }
    __syncthreads();

    int cur = 0;
    for (int t = 0; t < nk; ++t) {
        if (t + 1 < nk) {
            int koff = (t + 1) * 32;
            int nb = (cur ^ 1) * 4096;
#pragma unroll
            for (int i = 0; i < 2; ++i) {
                int ci = i * 256 + tid, row = ci >> 2, kc = (ci & 3) * 8;
                GLD16(A + (size_t)(m0 + row) * K + koff + kc, As + nb + ci * 8);
                GLD16(Bm + (size_t)(n0 + row) * K + koff + kc, Bs + nb + ci * 8);
            }
        }
        int cb = cur * 4096;
        bf16x8 af[4], bfv[4];
#pragma unroll
        for (int im = 0; im < 4; ++im)
            af[im] = *(const bf16x8*)&As[cb + (wr * 64 + im * 16 + c) * 32 + g * 8];
#pragma unroll
        for (int in = 0; in < 4; ++in)
            bfv[in] = *(const bf16x8*)&Bs[cb + (wc * 64 + in * 16 + c) * 32 + g * 8];
        __builtin_amdgcn_s_setprio(1);
#pragma unroll
        for (int im = 0; im < 4; ++im)
#pragma unroll
            for (int in = 0; in < 4; ++in)
                acc[im][in] = __builtin_amdgcn_mfma_f32_16x16x32_bf16(
                    af[im], bfv[in], acc[im][in], 0, 0, 0);
        __builtin_amdgcn_s_setprio(0);
        __syncthreads();
        cur ^= 1;
    }

#pragma unroll
    for (int im = 0; im < 4; ++im) {
#pragma unroll
        for (int in = 0; in < 4; ++in) {
            int col = n0 + wc * 64 + in * 16 + c;
            float bvc = biasrow ? 0.f : bias[col];
#pragma unroll
            for (int r = 0; r < 4; ++r) {
                int row = m0 + wr * 64 + im * 16 + g * 4 + r;
                float v = acc[im][in][r] + (biasrow ? bias[row] : bvc);
                Cb[(size_t)row * N + col] = (__bf16)v;
            }
        }
    }
}

// K-proj (128 tiles) + V^T-proj (128 tiles) merged into one 256-block dispatch.
__global__ __launch_bounds__(256)
void gemm_kv(const __bf16* __restrict__ kb, const __bf16* __restrict__ wkb,
             const float* __restrict__ bK, __bf16* __restrict__ kp,
             const __bf16* __restrict__ wvb, const __bf16* __restrict__ vb,
             const float* __restrict__ bV, __bf16* __restrict__ vpT) {
    __shared__ __bf16 As[2 * 128 * 32];
    __shared__ __bf16 Bs[2 * 128 * 32];
    const int bid = blockIdx.x;
    const int swz = (bid & 7) * 32 + (bid >> 3);   // 256 blocks
    if (swz < 128) {
        int bx = swz & 31, by = swz >> 5;
        gemm_tile(kb, wkb, bK, kp, 512, 2048, bx * 128, by * 128, 0, As, Bs);
    } else {
        int s2 = swz - 128;
        int bx = s2 & 3, by = s2 >> 2;
        gemm_tile(wvb, vb, bV, vpT, 4096, 2048, bx * 128, by * 128, 1, As, Bs);
    }
}

// ---------------------------------------------------------------------------
// Flash attention (unchanged from R5): 32x32x16 swapped-operand, XCD-exact
// placement, in-register softmax + defer-max, permlane P-fragments.
// ---------------------------------------------------------------------------
__global__ __launch_bounds__(256)
void attn_kernel(const __bf16* __restrict__ Qw, const __bf16* __restrict__ Kw,
                 const __bf16* __restrict__ VTw, __bf16* __restrict__ Ow) {
    constexpr int S = 2048, DQ = 2048, DKV = 512, TOK = 4096;
    const int bid = blockIdx.x;
    const int xcd = bid & 7, slot = bid >> 3;
    const int b = xcd >> 2, grp = xcd & 3;
    const int head = grp * 4 + (slot & 3);
    const int qblk = slot >> 2;
    const __bf16* Q   = Qw + (size_t)b * S * DQ + head * 128;
    const __bf16* Kp  = Kw + (size_t)b * S * DKV + grp * 128;
    const __bf16* VTp = VTw + (size_t)(grp * 128) * TOK + (size_t)b * S;
    __bf16* Op = Ow + (size_t)b * S * DQ + head * 128;

    __shared__ __bf16 Ks[2][64 * 128];
    __shared__ __bf16 Vs[2][128 * 64];

    const int tid = threadIdx.x, wid = tid >> 6, lane = tid & 63;
    const int ql = lane & 31, hi = lane >> 5;
    const int qrow = qblk * 128 + wid * 32 + ql;

    bf16x8 qf[8];
#pragma unroll
    for (int ks = 0; ks < 8; ++ks)
        qf[ks] = *(const bf16x8*)(Q + (size_t)qrow * DQ + ks * 16 + hi * 8);

    f32x16 o[4];
#pragma unroll
    for (int d = 0; d < 4; ++d)
#pragma unroll
        for (int r = 0; r < 16; ++r) o[d][r] = 0.f;
    float mprev = -1e30f, lsum = 0.f;
    constexpr float kexp = 0.08838834764831845f * 1.4426950408889634f;
    constexpr float THR = 8.0f / kexp;

    auto stage = [&](int buf, int t) {
#pragma unroll
        for (int i = 0; i < 4; ++i) {
            int ci = i * 256 + tid;
            int key = ci >> 4, ccl = ci & 15, ccg = ccl ^ (key & 15);
            GLD16(Kp + (size_t)(t * 64 + key) * DKV + ccg * 8, &Ks[buf][ci * 8]);
        }
#pragma unroll
        for (int i = 0; i < 4; ++i) {
            int ci = i * 256 + tid;
            int dh = ci >> 3, cl = ci & 7, cg = cl ^ ((dh ^ (dh >> 3)) & 7);
            GLD16(VTp + (size_t)dh * TOK + t * 64 + cg * 8, &Vs[buf][ci * 8]);
        }
    };

    stage(0, 0);
    __syncthreads();

    const int nt = S / 64;
    int cur = 0;
    for (int t = 0; t < nt; ++t) {
        if (t + 1 < nt) stage(cur ^ 1, t + 1);

        f32x16 sc[2];
        __builtin_amdgcn_s_setprio(1);
#pragma unroll
        for (int kt = 0; kt < 2; ++kt) {
#pragma unroll
            for (int r = 0; r < 16; ++r) sc[kt][r] = 0.f;
#pragma unroll
            for (int ks = 0; ks < 8; ++ks) {
                int key = kt * 32 + ql;
                int chl = (ks * 2 + hi) ^ (key & 15);
                bf16x8 kf = *(const bf16x8*)&Ks[cur][key * 128 + chl * 8];
                sc[kt] = __builtin_amdgcn_mfma_f32_32x32x16_bf16(kf, qf[ks], sc[kt], 0, 0, 0);
            }
        }
        __builtin_amdgcn_s_setprio(0);

        float mo = sc[0][0];
#pragma unroll
        for (int r = 1; r < 16; ++r) mo = fmaxf(mo, sc[0][r]);
#pragma unroll
        for (int r = 0; r < 16; ++r) mo = fmaxf(mo, sc[1][r]);
        mo = fmaxf(mo, __shfl_xor(mo, 32, 64));
        if (!__all(mo - mprev <= THR)) {
            float mn = fmaxf(mprev, mo);
            float ef = EXP2F((mprev - mn) * kexp);
            lsum *= ef;
#pragma unroll
            for (int d = 0; d < 4; ++d)
#pragma unroll
                for (int r = 0; r < 16; ++r) o[d][r] *= ef;
            mprev = mn;
        }
        float mnk = mprev * kexp;
        float rs = 0.f;
#pragma unroll
        for (int kt = 0; kt < 2; ++kt)
#pragma unroll
            for (int r = 0; r < 16; ++r) {
                float p = EXP2F(__builtin_fmaf(sc[kt][r], kexp, -mnk));
                sc[kt][r] = p;
                rs += p;
            }
        rs += __shfl_xor(rs, 32, 64);
        lsum += rs;

        unsigned pk[2][4][2];
#pragma unroll
        for (int kt = 0; kt < 2; ++kt)
#pragma unroll
            for (int rg = 0; rg < 4; ++rg) {
                pk[kt][rg][0] = pack2bf(sc[kt][rg * 4 + 0], sc[kt][rg * 4 + 1]);
                pk[kt][rg][1] = pack2bf(sc[kt][rg * 4 + 2], sc[kt][rg * 4 + 3]);
            }

        __builtin_amdgcn_s_setprio(1);
#pragma unroll
        for (int ks = 0; ks < 4; ++ks) {
            const int kt = ks >> 1, e = ks & 1;
            unsigned a0 = pk[kt][2 * e][0], b0 = pk[kt][2 * e + 1][0];
            unsigned a1 = pk[kt][2 * e][1], b1 = pk[kt][2 * e + 1][1];
            PLSWAP(a0, b0);
            PLSWAP(a1, b1);
            u32x4 fw = {a0, a1, b0, b1};
            bf16x8 pf = __builtin_bit_cast(bf16x8, fw);
#pragma unroll
            for (int dht = 0; dht < 4; ++dht) {
                int dh = dht * 32 + ql;
                int chl = (ks * 2 + hi) ^ ((dh ^ (dh >> 3)) & 7);
                bf16x8 vf = *(const bf16x8*)&Vs[cur][dh * 64 + chl * 8];
                o[dht] = __builtin_amdgcn_mfma_f32_32x32x16_bf16(vf, pf, o[dht], 0, 0, 0);
            }
        }
        __builtin_amdgcn_s_setprio(0);
        __syncthreads();
        cur ^= 1;
    }

    float inv = 1.0f / lsum;
#pragma unroll
    for (int dht = 0; dht < 4; ++dht)
#pragma unroll
        for (int rg = 0; rg < 4; ++rg) {
            bf16x4 wv;
#pragma unroll
            for (int j = 0; j < 4; ++j) wv[j] = (__bf16)(o[dht][rg * 4 + j] * inv);
            int dh0 = dht * 32 + rg * 8 + hi * 4;
            *(bf16x4*)(Op + (size_t)qrow * DQ + dh0) = wv;
        }
}

// ---------------------------------------------------------------------------
extern "C" void kernel_launch(void* const* d_in, const int* in_sizes, int n_in,
                              void* d_out, int out_size, void* d_ws, size_t ws_size,
                              hipStream_t stream) {
    (void)in_sizes; (void)n_in; (void)out_size; (void)ws_size;
    const float* query = (const float*)d_in[0];
    const float* key   = (const float*)d_in[1];
    const float* value = (const float*)d_in[2];
    const float* WQ = (const float*)d_in[3];
    const float* bQ = (const float*)d_in[4];
    const float* WK = (const float*)d_in[5];
    const float* bK = (const float*)d_in[6];
    const float* WV = (const float*)d_in[7];
    const float* bV = (const float*)d_in[8];
    const float* WO = (const float*)d_in[9];
    const float* bO = (const float*)d_in[10];
    float* out = (float*)d_out;

    __bf16* w = (__bf16*)d_ws;
    __bf16* qb  = w; w += (size_t)4096 * 2048;
    __bf16* kb  = w; w += (size_t)4096 * 2048;
    __bf16* vb  = w; w += (size_t)4096 * 2048;
    __bf16* wqb = w; w += (size_t)2048 * 2048;
    __bf16* wkb = w; w += (size_t)512 * 2048;
    __bf16* wvb = w; w += (size_t)512 * 2048;
    __bf16* wob = w; w += (size_t)2048 * 2048;
    __bf16* qp  = w; w += (size_t)4096 * 2048;  // Q proj [tok, 16*128]
    __bf16* kp  = w; w += (size_t)4096 * 512;   // K proj [tok, 4*128]
    __bf16* vpT = w; w += (size_t)512 * 4096;   // V proj transposed [4*128, tok]
    __bf16* ao  = w; w += (size_t)4096 * 2048;  // attention output

    auto conv = [&](const float* src, __bf16* dst, long n) {
        long n8 = n >> 3;
        long blocks = (n8 + 255) / 256;
        if (blocks > 2048) blocks = 2048;
        f2b_kernel<<<(int)blocks, 256, 0, stream>>>(src, dst, n8);
    };
    conv(query, qb, (long)4096 * 2048);
    conv(key,   kb, (long)4096 * 2048);
    conv(value, vb, (long)4096 * 2048);
    conv(WQ, wqb, (long)2048 * 2048);
    conv(WK, wkb, (long)512 * 2048);
    conv(WV, wvb, (long)512 * 2048);
    conv(WO, wob, (long)2048 * 2048);

    // Q projection: 256x128 tiles, 16x16 grid = 256 blocks (1/CU)
    gemm256<0><<<256, 512, 0, stream>>>(qb, wqb, bQ, nullptr, qp, 4096, 2048, 2048, 16);
    // K + V^T projections (m97 structure, 256 blocks)
    gemm_kv<<<256, 256, 0, stream>>>(kb, wkb, bK, kp, wvb, vb, bV, vpT);

    // flash attention: XCD-exact (b,grp) placement
    attn_kernel<<<512, 256, 0, stream>>>(qp, kp, vpT, ao);

    // output projection (fp32 out)
    gemm256<1><<<256, 512, 0, stream>>>(ao, wob, bO, out, nullptr, 4096, 2048, 2048, 16);
}

// Round 7
// 292.340 us; speedup vs baseline: 2.0922x; 1.0017x over previous
//
#include <hip/hip_runtime.h>
#include <cstdint>
#include <cstddef>

// ---------------------------------------------------------------------------
// Fused GQA MHA: B=2 S=2048 D=2048, G=4 HPG=4 DH=128 (16 heads)
// fused fp32->bf16 | gemm256 (Q proj) + gemm_kv (K, V^T) | flash attn | O proj
// ---------------------------------------------------------------------------

typedef __attribute__((ext_vector_type(8)))  __bf16 bf16x8;
typedef __attribute__((ext_vector_type(4)))  __bf16 bf16x4;
typedef __attribute__((ext_vector_type(4)))  float  f32x4;
typedef __attribute__((ext_vector_type(16))) float  f32x16;
typedef __attribute__((ext_vector_type(4)))  unsigned int u32x4;

#define GLD16(gp, lp) __builtin_amdgcn_global_load_lds(                         \
    (__attribute__((address_space(1))) void*)(size_t)(gp),                     \
    (__attribute__((address_space(3))) void*)(lp), 16, 0, 0)

#define PLSWAP(a, b) asm volatile("v_permlane32_swap_b32 %0, %1" : "+v"(a), "+v"(b))
#define EXP2F(x) __builtin_amdgcn_exp2f(x)

static __device__ __forceinline__ unsigned pack2bf(float a, float b) {
    unsigned short ua = __builtin_bit_cast(unsigned short, (__bf16)a);
    unsigned short ub = __builtin_bit_cast(unsigned short, (__bf16)b);
    return (unsigned)ua | ((unsigned)ub << 16);
}

// ---------------------------------------------------------------------------
// Fused fp32->bf16 for all 7 tensors in one launch (grid-stride, 8 elem/thread)
// ---------------------------------------------------------------------------
struct F2BArgs {
    const float* src[7];
    __bf16* dst[7];
    long beg[8];   // prefix sums, units of 8-element chunks
};
__global__ void f2b_multi(F2BArgs a) {
    const long total = a.beg[7];
    const long stride = (long)gridDim.x * blockDim.x;
    for (long i = (long)blockIdx.x * blockDim.x + threadIdx.x; i < total; i += stride) {
        int s = 0;
#pragma unroll
        for (int j = 1; j < 7; ++j) s += (i >= a.beg[j]);
        long off = i - a.beg[s];
        const float4* p = (const float4*)(a.src[s] + off * 8);
        float4 x = p[0], y = p[1];
        bf16x8 r;
        r[0] = (__bf16)x.x; r[1] = (__bf16)x.y; r[2] = (__bf16)x.z; r[3] = (__bf16)x.w;
        r[4] = (__bf16)y.x; r[5] = (__bf16)y.y; r[6] = (__bf16)y.z; r[7] = (__bf16)y.w;
        *(bf16x8*)(a.dst[s] + off * 8) = r;
    }
}

// ---------------------------------------------------------------------------
// gemm256: BM=256 BN=128 BK=64, 8 waves, triple-buffered, counted vmcnt(6)
// (unchanged from R6 — verified)
// ---------------------------------------------------------------------------
template <int OUTF32>
__global__ __launch_bounds__(512)
void gemm256(const __bf16* __restrict__ A, const __bf16* __restrict__ Bm,
             const float* __restrict__ bias, float* __restrict__ Cf,
             __bf16* __restrict__ Cb, int M, int N, int K, int nbx) {
    __shared__ __bf16 As[3][256 * 64];
    __shared__ __bf16 Bs[3][128 * 64];
    const int tid = threadIdx.x, lane = tid & 63, wid = tid >> 6;
    const int g = lane >> 4, c = lane & 15;
    const int wr = wid >> 1, wc = wid & 1;
    const int cpx = gridDim.x >> 3;
    const int swz = ((int)blockIdx.x & 7) * cpx + ((int)blockIdx.x >> 3);
    const int bx = swz % nbx, by = swz / nbx;
    const int m0 = by * 256, n0 = bx * 128;
    const int nkt = K >> 6;

    const f32x4 z = {0.f, 0.f, 0.f, 0.f};
    f32x4 acc[4][4];
#pragma unroll
    for (int i = 0; i < 4; ++i)
#pragma unroll
        for (int j = 0; j < 4; ++j) acc[i][j] = z;

    auto stageA = [&](int b, int kt, int h) {
        if (kt >= nkt) return;
        const __bf16* src = A + (size_t)m0 * K + (size_t)kt * 64;
#pragma unroll
        for (int i = 0; i < 2; ++i) {
            int ci = h * 1024 + i * 512 + tid;
            int row = ci >> 3, chg = (ci & 7) ^ (row & 7);
            GLD16(src + (size_t)row * K + chg * 8, &As[b][ci * 8]);
        }
    };
    auto stageB = [&](int b, int kt) {
        if (kt >= nkt) return;
        const __bf16* src = Bm + (size_t)n0 * K + (size_t)kt * 64;
#pragma unroll
        for (int i = 0; i < 2; ++i) {
            int ci = i * 512 + tid;
            int row = ci >> 3, chg = (ci & 7) ^ (row & 7);
            GLD16(src + (size_t)row * K + chg * 8, &Bs[b][ci * 8]);
        }
    };

    stageA(0, 0, 0); stageA(0, 0, 1); stageB(0, 0);
    stageA(1, 1, 0); stageA(1, 1, 1); stageB(1, 1);
    asm volatile("s_waitcnt vmcnt(6)" ::: "memory");
    __builtin_amdgcn_sched_barrier(0);
    __builtin_amdgcn_s_barrier();

    int bd = 0;
    for (int kt = 0; kt < nkt; ++kt) {
        const int bs = (bd >= 1) ? bd - 1 : 2;
        bf16x8 af[4], bfr[4];
#pragma unroll
        for (int ph = 0; ph < 2; ++ph) {
#pragma unroll
            for (int mi = 0; mi < 4; ++mi) {
                int row = wr * 64 + mi * 16 + c;
                int ch = (ph * 4 + g) ^ (c & 7);
                af[mi] = *(const bf16x8*)&As[bd][row * 64 + ch * 8];
            }
#pragma unroll
            for (int ni = 0; ni < 4; ++ni) {
                int row = wc * 64 + ni * 16 + c;
                int ch = (ph * 4 + g) ^ (c & 7);
                bfr[ni] = *(const bf16x8*)&Bs[bd][row * 64 + ch * 8];
            }
            if (ph == 0) {
                stageA(bs, kt + 2, 0);
            } else {
                stageA(bs, kt + 2, 1);
                stageB(bs, kt + 2);
            }
            __builtin_amdgcn_s_barrier();
            asm volatile("s_waitcnt lgkmcnt(0)" ::: "memory");
            __builtin_amdgcn_sched_barrier(0);
            __builtin_amdgcn_s_setprio(1);
#pragma unroll
            for (int mi = 0; mi < 4; ++mi)
#pragma unroll
                for (int ni = 0; ni < 4; ++ni)
                    acc[mi][ni] = __builtin_amdgcn_mfma_f32_16x16x32_bf16(
                        af[mi], bfr[ni], acc[mi][ni], 0, 0, 0);
            __builtin_amdgcn_s_setprio(0);
            if (ph == 1) {
                if (kt >= nkt - 2) asm volatile("s_waitcnt vmcnt(0)" ::: "memory");
                else               asm volatile("s_waitcnt vmcnt(6)" ::: "memory");
                __builtin_amdgcn_sched_barrier(0);
            }
            __builtin_amdgcn_s_barrier();
        }
        bd = (bd >= 2) ? 0 : bd + 1;
    }

#pragma unroll
    for (int mi = 0; mi < 4; ++mi) {
#pragma unroll
        for (int ni = 0; ni < 4; ++ni) {
            int col = n0 + wc * 64 + ni * 16 + c;
            float bvc = bias[col];
#pragma unroll
            for (int r = 0; r < 4; ++r) {
                int row = m0 + wr * 64 + mi * 16 + g * 4 + r;
                float v = acc[mi][ni][r] + bvc;
                if (OUTF32) Cf[(size_t)row * N + col] = v;
                else        Cb[(size_t)row * N + col] = (__bf16)v;
            }
        }
    }
}

// ---------------------------------------------------------------------------
// m97-structure tile body for the small K/V projections (unchanged)
// ---------------------------------------------------------------------------
static __device__ __forceinline__
void gemm_tile(const __bf16* __restrict__ A, const __bf16* __restrict__ Bm,
               const float* __restrict__ bias,
               __bf16* __restrict__ Cb, int N, int K, int m0, int n0, int biasrow,
               __bf16* As, __bf16* Bs) {
    const int tid = threadIdx.x;
    const int lane = tid & 63, wid = tid >> 6;
    const int g = lane >> 4, c = lane & 15;
    const int wr = wid >> 1, wc = wid & 1;

    const f32x4 z = {0.f, 0.f, 0.f, 0.f};
    f32x4 acc[4][4];
#pragma unroll
    for (int i = 0; i < 4; ++i)
#pragma unroll
        for (int j = 0; j < 4; ++j) acc[i][j] = z;

    const int nk = K >> 5;
#pragma unroll
    for (int i = 0; i < 2; ++i) {
        int ci = i * 256 + tid, row = ci >> 2, kc = (ci & 3) * 8;
        GLD16(A + (size_t)(m0 + row) * K + kc, As + ci * 8);
        GLD16(Bm + (size_t)(n0 + row) * K + kc, Bs + ci * 8);
    }
    __syncthreads();

    int cur = 0;
    for (int t = 0; t < nk; ++t) {
        if (t + 1 < nk) {
            int koff = (t + 1) * 32;
            int nb = (cur ^ 1) * 4096;
#pragma unroll
            for (int i = 0; i < 2; ++i) {
                int ci = i * 256 + tid, row = ci >> 2, kc = (ci & 3) * 8;
                GLD16(A + (size_t)(m0 + row) * K + koff + kc, As + nb + ci * 8);
                GLD16(Bm + (size_t)(n0 + row) * K + koff + kc, Bs + nb + ci * 8);
            }
        }
        int cb = cur * 4096;
        bf16x8 af[4], bfv[4];
#pragma unroll
        for (int im = 0; im < 4; ++im)
            af[im] = *(const bf16x8*)&As[cb + (wr * 64 + im * 16 + c) * 32 + g * 8];
#pragma unroll
        for (int in = 0; in < 4; ++in)
            bfv[in] = *(const bf16x8*)&Bs[cb + (wc * 64 + in * 16 + c) * 32 + g * 8];
        __builtin_amdgcn_s_setprio(1);
#pragma unroll
        for (int im = 0; im < 4; ++im)
#pragma unroll
            for (int in = 0; in < 4; ++in)
                acc[im][in] = __builtin_amdgcn_mfma_f32_16x16x32_bf16(
                    af[im], bfv[in], acc[im][in], 0, 0, 0);
        __builtin_amdgcn_s_setprio(0);
        __syncthreads();
        cur ^= 1;
    }

#pragma unroll
    for (int im = 0; im < 4; ++im) {
#pragma unroll
        for (int in = 0; in < 4; ++in) {
            int col = n0 + wc * 64 + in * 16 + c;
            float bvc = biasrow ? 0.f : bias[col];
#pragma unroll
            for (int r = 0; r < 4; ++r) {
                int row = m0 + wr * 64 + im * 16 + g * 4 + r;
                float v = acc[im][in][r] + (biasrow ? bias[row] : bvc);
                Cb[(size_t)row * N + col] = (__bf16)v;
            }
        }
    }
}

__global__ __launch_bounds__(256)
void gemm_kv(const __bf16* __restrict__ kb, const __bf16* __restrict__ wkb,
             const float* __restrict__ bK, __bf16* __restrict__ kp,
             const __bf16* __restrict__ wvb, const __bf16* __restrict__ vb,
             const float* __restrict__ bV, __bf16* __restrict__ vpT) {
    __shared__ __bf16 As[2 * 128 * 32];
    __shared__ __bf16 Bs[2 * 128 * 32];
    const int bid = blockIdx.x;
    const int swz = (bid & 7) * 32 + (bid >> 3);
    if (swz < 128) {
        int bx = swz & 31, by = swz >> 5;
        gemm_tile(kb, wkb, bK, kp, 512, 2048, bx * 128, by * 128, 0, As, Bs);
    } else {
        int s2 = swz - 128;
        int bx = s2 & 3, by = s2 >> 2;
        gemm_tile(wvb, vb, bV, vpT, 4096, 2048, bx * 128, by * 128, 1, As, Bs);
    }
}

// ---------------------------------------------------------------------------
// Flash attention: 32x32x16 swapped-operand + tile-level software pipeline.
// K triple-buffered, V double-buffered (80 KB). Iter t: softmax(t) [tree
// reductions], then interleaved MFMA cluster {QK^T(t+1) || PV(t)}, one barrier.
// ---------------------------------------------------------------------------
__global__ __launch_bounds__(256)
void attn_kernel(const __bf16* __restrict__ Qw, const __bf16* __restrict__ Kw,
                 const __bf16* __restrict__ VTw, __bf16* __restrict__ Ow) {
    constexpr int S = 2048, DQ = 2048, DKV = 512, TOK = 4096;
    constexpr int nt = S / 64;
    const int bid = blockIdx.x;
    const int xcd = bid & 7, slot = bid >> 3;
    const int b = xcd >> 2, grp = xcd & 3;
    const int head = grp * 4 + (slot & 3);
    const int qblk = slot >> 2;
    const __bf16* Q   = Qw + (size_t)b * S * DQ + head * 128;
    const __bf16* Kp  = Kw + (size_t)b * S * DKV + grp * 128;
    const __bf16* VTp = VTw + (size_t)(grp * 128) * TOK + (size_t)b * S;
    __bf16* Op = Ow + (size_t)b * S * DQ + head * 128;

    __shared__ __bf16 Ks[3][64 * 128];   // 48 KB
    __shared__ __bf16 Vs[2][128 * 64];   // 32 KB

    const int tid = threadIdx.x, wid = tid >> 6, lane = tid & 63;
    const int ql = lane & 31, hi = lane >> 5;
    const int qrow = qblk * 128 + wid * 32 + ql;

    bf16x8 qf[8];
#pragma unroll
    for (int ks = 0; ks < 8; ++ks)
        qf[ks] = *(const bf16x8*)(Q + (size_t)qrow * DQ + ks * 16 + hi * 8);

    f32x16 o[4];
#pragma unroll
    for (int d = 0; d < 4; ++d)
#pragma unroll
        for (int r = 0; r < 16; ++r) o[d][r] = 0.f;
    float mprev = -1e30f, lsum = 0.f;
    constexpr float kexp = 0.08838834764831845f * 1.4426950408889634f;
    constexpr float THR = 8.0f / kexp;

    auto stageK = [&](int buf, int t) {
#pragma unroll
        for (int i = 0; i < 4; ++i) {
            int ci = i * 256 + tid;
            int key = ci >> 4, ccl = ci & 15, ccg = ccl ^ (key & 15);
            GLD16(Kp + (size_t)(t * 64 + key) * DKV + ccg * 8, &Ks[buf][ci * 8]);
        }
    };
    auto stageV = [&](int buf, int t) {
#pragma unroll
        for (int i = 0; i < 4; ++i) {
            int ci = i * 256 + tid;
            int dh = ci >> 3, cl = ci & 7, cg = cl ^ ((dh ^ (dh >> 3)) & 7);
            GLD16(VTp + (size_t)dh * TOK + t * 64 + cg * 8, &Vs[buf][ci * 8]);
        }
    };

    // prologue: K0, K1, V0 staged; QK^T(0)
    stageK(0, 0); stageK(1, 1); stageV(0, 0);
    __syncthreads();

    f32x16 scA[2], scB[2];
#pragma unroll
    for (int kt = 0; kt < 2; ++kt)
#pragma unroll
        for (int r = 0; r < 16; ++r) scA[kt][r] = 0.f;
    __builtin_amdgcn_s_setprio(1);
#pragma unroll
    for (int kt = 0; kt < 2; ++kt)
#pragma unroll
        for (int ks = 0; ks < 8; ++ks) {
            int key = kt * 32 + ql;
            int chl = (ks * 2 + hi) ^ (key & 15);
            bf16x8 kf = *(const bf16x8*)&Ks[0][key * 128 + chl * 8];
            scA[kt] = __builtin_amdgcn_mfma_f32_32x32x16_bf16(kf, qf[ks], scA[kt], 0, 0, 0);
        }
    __builtin_amdgcn_s_setprio(0);

    // body: softmax(t) on scc; interleaved {QK^T(t+1)->scn || PV(t)}
    auto body = [&](int t, f32x16 (&scc)[2], f32x16 (&scn)[2]) {
        const bool hasN = (t + 1) < nt;
        if (t + 2 < nt) stageK((t + 2) % 3, t + 2);
        if (hasN)       stageV((t + 1) & 1, t + 1);

        // ---- softmax: tree max (depth 5)
        float mx[16];
#pragma unroll
        for (int r = 0; r < 16; ++r) mx[r] = fmaxf(scc[0][r], scc[1][r]);
#pragma unroll
        for (int w = 8; w >= 1; w >>= 1)
#pragma unroll
            for (int r = 0; r < w; ++r) mx[r] = fmaxf(mx[r], mx[r + w]);
        float mo = fmaxf(mx[0], __shfl_xor(mx[0], 32, 64));
        if (!__all(mo - mprev <= THR)) {          // T13 defer-max
            float mn = fmaxf(mprev, mo);
            float ef = EXP2F((mprev - mn) * kexp);
            lsum *= ef;
#pragma unroll
            for (int d = 0; d < 4; ++d)
#pragma unroll
                for (int r = 0; r < 16; ++r) o[d][r] *= ef;
            mprev = mn;
        }
        float mnk = mprev * kexp;
#pragma unroll
        for (int kt = 0; kt < 2; ++kt)
#pragma unroll
            for (int r = 0; r < 16; ++r)
                scc[kt][r] = EXP2F(__builtin_fmaf(scc[kt][r], kexp, -mnk));
        float sm[16];
#pragma unroll
        for (int r = 0; r < 16; ++r) sm[r] = scc[0][r] + scc[1][r];
#pragma unroll
        for (int w = 8; w >= 1; w >>= 1)
#pragma unroll
            for (int r = 0; r < w; ++r) sm[r] += sm[r + w];
        lsum += sm[0] + __shfl_xor(sm[0], 32, 64);

        // ---- pack P (keys {0..3}+8rg+4hi+32kt per pk[kt][rg])
        unsigned pk[2][4][2];
#pragma unroll
        for (int kt = 0; kt < 2; ++kt)
#pragma unroll
            for (int rg = 0; rg < 4; ++rg) {
                pk[kt][rg][0] = pack2bf(scc[kt][rg * 4 + 0], scc[kt][rg * 4 + 1]);
                pk[kt][rg][1] = pack2bf(scc[kt][rg * 4 + 2], scc[kt][rg * 4 + 3]);
            }

        // ---- interleaved MFMA cluster: QK^T(t+1) from Ks[(t+1)%3] || PV(t)
        const __bf16* kbp = &Ks[(t + 1) % 3][0];
        const __bf16* vbp = &Vs[t & 1][0];
        if (hasN) {
#pragma unroll
            for (int kt = 0; kt < 2; ++kt)
#pragma unroll
                for (int r = 0; r < 16; ++r) scn[kt][r] = 0.f;
        }
        __builtin_amdgcn_s_setprio(1);
#pragma unroll
        for (int ks = 0; ks < 8; ++ks) {
            if (hasN) {
#pragma unroll
                for (int kt = 0; kt < 2; ++kt) {
                    int key = kt * 32 + ql;
                    int chl = (ks * 2 + hi) ^ (key & 15);
                    bf16x8 kf = *(const bf16x8*)&kbp[key * 128 + chl * 8];
                    scn[kt] = __builtin_amdgcn_mfma_f32_32x32x16_bf16(kf, qf[ks], scn[kt], 0, 0, 0);
                }
            }
            if ((ks & 1) == 0) {
                const int s = ks >> 1, kt2 = s >> 1, e = s & 1;
                unsigned a0 = pk[kt2][2 * e][0], b0 = pk[kt2][2 * e + 1][0];
                unsigned a1 = pk[kt2][2 * e][1], b1 = pk[kt2][2 * e + 1][1];
                PLSWAP(a0, b0);
                PLSWAP(a1, b1);
                u32x4 fw = {a0, a1, b0, b1};
                bf16x8 pf = __builtin_bit_cast(bf16x8, fw);
#pragma unroll
                for (int dht = 0; dht < 4; ++dht) {
                    int dh = dht * 32 + ql;
                    int chl = (s * 2 + hi) ^ ((dh ^ (dh >> 3)) & 7);
                    bf16x8 vf = *(const bf16x8*)&vbp[dh * 64 + chl * 8];
                    o[dht] = __builtin_amdgcn_mfma_f32_32x32x16_bf16(vf, pf, o[dht], 0, 0, 0);
                }
            }
        }
        __builtin_amdgcn_s_setprio(0);
        __syncthreads();   // drains vmcnt: this iter's stages landed; LDS reads done
    };

    for (int t = 0; t < nt; t += 2) {
        body(t, scA, scB);
        body(t + 1, scB, scA);
    }

    // ---- epilogue
    float inv = 1.0f / lsum;
#pragma unroll
    for (int dht = 0; dht < 4; ++dht)
#pragma unroll
        for (int rg = 0; rg < 4; ++rg) {
            bf16x4 wv;
#pragma unroll
            for (int j = 0; j < 4; ++j) wv[j] = (__bf16)(o[dht][rg * 4 + j] * inv);
            int dh0 = dht * 32 + rg * 8 + hi * 4;
            *(bf16x4*)(Op + (size_t)qrow * DQ + dh0) = wv;
        }
}

// ---------------------------------------------------------------------------
extern "C" void kernel_launch(void* const* d_in, const int* in_sizes, int n_in,
                              void* d_out, int out_size, void* d_ws, size_t ws_size,
                              hipStream_t stream) {
    (void)in_sizes; (void)n_in; (void)out_size; (void)ws_size;
    const float* query = (const float*)d_in[0];
    const float* key   = (const float*)d_in[1];
    const float* value = (const float*)d_in[2];
    const float* WQ = (const float*)d_in[3];
    const float* bQ = (const float*)d_in[4];
    const float* WK = (const float*)d_in[5];
    const float* bK = (const float*)d_in[6];
    const float* WV = (const float*)d_in[7];
    const float* bV = (const float*)d_in[8];
    const float* WO = (const float*)d_in[9];
    const float* bO = (const float*)d_in[10];
    float* out = (float*)d_out;

    __bf16* w = (__bf16*)d_ws;
    __bf16* qb  = w; w += (size_t)4096 * 2048;
    __bf16* kb  = w; w += (size_t)4096 * 2048;
    __bf16* vb  = w; w += (size_t)4096 * 2048;
    __bf16* wqb = w; w += (size_t)2048 * 2048;
    __bf16* wkb = w; w += (size_t)512 * 2048;
    __bf16* wvb = w; w += (size_t)512 * 2048;
    __bf16* wob = w; w += (size_t)2048 * 2048;
    __bf16* qp  = w; w += (size_t)4096 * 2048;
    __bf16* kp  = w; w += (size_t)4096 * 512;
    __bf16* vpT = w; w += (size_t)512 * 4096;
    __bf16* ao  = w; w += (size_t)4096 * 2048;

    // fused convert: one launch for all 7 tensors
    F2BArgs fa;
    fa.src[0] = query; fa.dst[0] = qb;
    fa.src[1] = key;   fa.dst[1] = kb;
    fa.src[2] = value; fa.dst[2] = vb;
    fa.src[3] = WQ;    fa.dst[3] = wqb;
    fa.src[4] = WK;    fa.dst[4] = wkb;
    fa.src[5] = WV;    fa.dst[5] = wvb;
    fa.src[6] = WO;    fa.dst[6] = wob;
    const long n8s[7] = {1048576, 1048576, 1048576, 524288, 131072, 131072, 524288};
    long acc = 0;
    for (int i = 0; i < 7; ++i) { fa.beg[i] = acc; acc += n8s[i]; }
    fa.beg[7] = acc;
    f2b_multi<<<2048, 256, 0, stream>>>(fa);

    gemm256<0><<<256, 512, 0, stream>>>(qb, wqb, bQ, nullptr, qp, 4096, 2048, 2048, 16);
    gemm_kv<<<256, 256, 0, stream>>>(kb, wkb, bK, kp, wvb, vb, bV, vpT);

    attn_kernel<<<512, 256, 0, stream>>>(qp, kp, vpT, ao);

    gemm256<1><<<256, 512, 0, stream>>>(ao, wob, bO, out, nullptr, 4096, 2048, 2048, 16);
}

// Round 8
// 271.285 us; speedup vs baseline: 2.2545x; 1.0776x over previous
//
#include <hip/hip_runtime.h>
#include <cstdint>
#include <cstddef>

// ---------------------------------------------------------------------------
// Fused GQA MHA: B=2 S=2048 D=2048, G=4 HPG=4 DH=128 (16 heads)
// fused fp32->bf16 | gemm256 (Q proj) + gemm_kv (K, V^T) | flash attn | O proj
// ---------------------------------------------------------------------------

typedef __attribute__((ext_vector_type(8)))  __bf16 bf16x8;
typedef __attribute__((ext_vector_type(4)))  __bf16 bf16x4;
typedef __attribute__((ext_vector_type(4)))  float  f32x4;
typedef __attribute__((ext_vector_type(16))) float  f32x16;
typedef __attribute__((ext_vector_type(4)))  unsigned int u32x4;

#define GLD16(gp, lp) __builtin_amdgcn_global_load_lds(                         \
    (__attribute__((address_space(1))) void*)(size_t)(gp),                     \
    (__attribute__((address_space(3))) void*)(lp), 16, 0, 0)

#define PLSWAP(a, b) asm volatile("v_permlane32_swap_b32 %0, %1" : "+v"(a), "+v"(b))
#define EXP2F(x) __builtin_amdgcn_exp2f(x)

static __device__ __forceinline__ unsigned pack2bf(float a, float b) {
    unsigned short ua = __builtin_bit_cast(unsigned short, (__bf16)a);
    unsigned short ub = __builtin_bit_cast(unsigned short, (__bf16)b);
    return (unsigned)ua | ((unsigned)ub << 16);
}

// ---------------------------------------------------------------------------
// Fused fp32->bf16 for all 7 tensors in one launch
// ---------------------------------------------------------------------------
struct F2BArgs {
    const float* src[7];
    __bf16* dst[7];
    long beg[8];   // prefix sums, units of 8-element chunks
};
__global__ void f2b_multi(F2BArgs a) {
    const long total = a.beg[7];
    const long stride = (long)gridDim.x * blockDim.x;
    for (long i = (long)blockIdx.x * blockDim.x + threadIdx.x; i < total; i += stride) {
        int s = 0;
#pragma unroll
        for (int j = 1; j < 7; ++j) s += (i >= a.beg[j]);
        long off = i - a.beg[s];
        const float4* p = (const float4*)(a.src[s] + off * 8);
        float4 x = p[0], y = p[1];
        bf16x8 r;
        r[0] = (__bf16)x.x; r[1] = (__bf16)x.y; r[2] = (__bf16)x.z; r[3] = (__bf16)x.w;
        r[4] = (__bf16)y.x; r[5] = (__bf16)y.y; r[6] = (__bf16)y.z; r[7] = (__bf16)y.w;
        *(bf16x8*)(a.dst[s] + off * 8) = r;
    }
}

// ---------------------------------------------------------------------------
// gemm256: BM=256 BN=128 BK=64, 8 waves, triple-buffered, counted vmcnt(6)
// (unchanged — verified R6)
// ---------------------------------------------------------------------------
template <int OUTF32>
__global__ __launch_bounds__(512)
void gemm256(const __bf16* __restrict__ A, const __bf16* __restrict__ Bm,
             const float* __restrict__ bias, float* __restrict__ Cf,
             __bf16* __restrict__ Cb, int M, int N, int K, int nbx) {
    __shared__ __bf16 As[3][256 * 64];
    __shared__ __bf16 Bs[3][128 * 64];
    const int tid = threadIdx.x, lane = tid & 63, wid = tid >> 6;
    const int g = lane >> 4, c = lane & 15;
    const int wr = wid >> 1, wc = wid & 1;
    const int cpx = gridDim.x >> 3;
    const int swz = ((int)blockIdx.x & 7) * cpx + ((int)blockIdx.x >> 3);
    const int bx = swz % nbx, by = swz / nbx;
    const int m0 = by * 256, n0 = bx * 128;
    const int nkt = K >> 6;

    const f32x4 z = {0.f, 0.f, 0.f, 0.f};
    f32x4 acc[4][4];
#pragma unroll
    for (int i = 0; i < 4; ++i)
#pragma unroll
        for (int j = 0; j < 4; ++j) acc[i][j] = z;

    auto stageA = [&](int b, int kt, int h) {
        if (kt >= nkt) return;
        const __bf16* src = A + (size_t)m0 * K + (size_t)kt * 64;
#pragma unroll
        for (int i = 0; i < 2; ++i) {
            int ci = h * 1024 + i * 512 + tid;
            int row = ci >> 3, chg = (ci & 7) ^ (row & 7);
            GLD16(src + (size_t)row * K + chg * 8, &As[b][ci * 8]);
        }
    };
    auto stageB = [&](int b, int kt) {
        if (kt >= nkt) return;
        const __bf16* src = Bm + (size_t)n0 * K + (size_t)kt * 64;
#pragma unroll
        for (int i = 0; i < 2; ++i) {
            int ci = i * 512 + tid;
            int row = ci >> 3, chg = (ci & 7) ^ (row & 7);
            GLD16(src + (size_t)row * K + chg * 8, &Bs[b][ci * 8]);
        }
    };

    stageA(0, 0, 0); stageA(0, 0, 1); stageB(0, 0);
    stageA(1, 1, 0); stageA(1, 1, 1); stageB(1, 1);
    asm volatile("s_waitcnt vmcnt(6)" ::: "memory");
    __builtin_amdgcn_sched_barrier(0);
    __builtin_amdgcn_s_barrier();

    int bd = 0;
    for (int kt = 0; kt < nkt; ++kt) {
        const int bs = (bd >= 1) ? bd - 1 : 2;
        bf16x8 af[4], bfr[4];
#pragma unroll
        for (int ph = 0; ph < 2; ++ph) {
#pragma unroll
            for (int mi = 0; mi < 4; ++mi) {
                int row = wr * 64 + mi * 16 + c;
                int ch = (ph * 4 + g) ^ (c & 7);
                af[mi] = *(const bf16x8*)&As[bd][row * 64 + ch * 8];
            }
#pragma unroll
            for (int ni = 0; ni < 4; ++ni) {
                int row = wc * 64 + ni * 16 + c;
                int ch = (ph * 4 + g) ^ (c & 7);
                bfr[ni] = *(const bf16x8*)&Bs[bd][row * 64 + ch * 8];
            }
            if (ph == 0) {
                stageA(bs, kt + 2, 0);
            } else {
                stageA(bs, kt + 2, 1);
                stageB(bs, kt + 2);
            }
            __builtin_amdgcn_s_barrier();
            asm volatile("s_waitcnt lgkmcnt(0)" ::: "memory");
            __builtin_amdgcn_sched_barrier(0);
            __builtin_amdgcn_s_setprio(1);
#pragma unroll
            for (int mi = 0; mi < 4; ++mi)
#pragma unroll
                for (int ni = 0; ni < 4; ++ni)
                    acc[mi][ni] = __builtin_amdgcn_mfma_f32_16x16x32_bf16(
                        af[mi], bfr[ni], acc[mi][ni], 0, 0, 0);
            __builtin_amdgcn_s_setprio(0);
            if (ph == 1) {
                if (kt >= nkt - 2) asm volatile("s_waitcnt vmcnt(0)" ::: "memory");
                else               asm volatile("s_waitcnt vmcnt(6)" ::: "memory");
                __builtin_amdgcn_sched_barrier(0);
            }
            __builtin_amdgcn_s_barrier();
        }
        bd = (bd >= 2) ? 0 : bd + 1;
    }

#pragma unroll
    for (int mi = 0; mi < 4; ++mi) {
#pragma unroll
        for (int ni = 0; ni < 4; ++ni) {
            int col = n0 + wc * 64 + ni * 16 + c;
            float bvc = bias[col];
#pragma unroll
            for (int r = 0; r < 4; ++r) {
                int row = m0 + wr * 64 + mi * 16 + g * 4 + r;
                float v = acc[mi][ni][r] + bvc;
                if (OUTF32) Cf[(size_t)row * N + col] = v;
                else        Cb[(size_t)row * N + col] = (__bf16)v;
            }
        }
    }
}

// ---------------------------------------------------------------------------
// m97-structure tile body for the small K/V projections (unchanged)
// ---------------------------------------------------------------------------
static __device__ __forceinline__
void gemm_tile(const __bf16* __restrict__ A, const __bf16* __restrict__ Bm,
               const float* __restrict__ bias,
               __bf16* __restrict__ Cb, int N, int K, int m0, int n0, int biasrow,
               __bf16* As, __bf16* Bs) {
    const int tid = threadIdx.x;
    const int lane = tid & 63, wid = tid >> 6;
    const int g = lane >> 4, c = lane & 15;
    const int wr = wid >> 1, wc = wid & 1;

    const f32x4 z = {0.f, 0.f, 0.f, 0.f};
    f32x4 acc[4][4];
#pragma unroll
    for (int i = 0; i < 4; ++i)
#pragma unroll
        for (int j = 0; j < 4; ++j) acc[i][j] = z;

    const int nk = K >> 5;
#pragma unroll
    for (int i = 0; i < 2; ++i) {
        int ci = i * 256 + tid, row = ci >> 2, kc = (ci & 3) * 8;
        GLD16(A + (size_t)(m0 + row) * K + kc, As + ci * 8);
        GLD16(Bm + (size_t)(n0 + row) * K + kc, Bs + ci * 8);
    }
    __syncthreads();

    int cur = 0;
    for (int t = 0; t < nk; ++t) {
        if (t + 1 < nk) {
            int koff = (t + 1) * 32;
            int nb = (cur ^ 1) * 4096;
#pragma unroll
            for (int i = 0; i < 2; ++i) {
                int ci = i * 256 + tid, row = ci >> 2, kc = (ci & 3) * 8;
                GLD16(A + (size_t)(m0 + row) * K + koff + kc, As + nb + ci * 8);
                GLD16(Bm + (size_t)(n0 + row) * K + koff + kc, Bs + nb + ci * 8);
            }
        }
        int cb = cur * 4096;
        bf16x8 af[4], bfv[4];
#pragma unroll
        for (int im = 0; im < 4; ++im)
            af[im] = *(const bf16x8*)&As[cb + (wr * 64 + im * 16 + c) * 32 + g * 8];
#pragma unroll
        for (int in = 0; in < 4; ++in)
            bfv[in] = *(const bf16x8*)&Bs[cb + (wc * 64 + in * 16 + c) * 32 + g * 8];
        __builtin_amdgcn_s_setprio(1);
#pragma unroll
        for (int im = 0; im < 4; ++im)
#pragma unroll
            for (int in = 0; in < 4; ++in)
                acc[im][in] = __builtin_amdgcn_mfma_f32_16x16x32_bf16(
                    af[im], bfv[in], acc[im][in], 0, 0, 0);
        __builtin_amdgcn_s_setprio(0);
        __syncthreads();
        cur ^= 1;
    }

#pragma unroll
    for (int im = 0; im < 4; ++im) {
#pragma unroll
        for (int in = 0; in < 4; ++in) {
            int col = n0 + wc * 64 + in * 16 + c;
            float bvc = biasrow ? 0.f : bias[col];
#pragma unroll
            for (int r = 0; r < 4; ++r) {
                int row = m0 + wr * 64 + im * 16 + g * 4 + r;
                float v = acc[im][in][r] + (biasrow ? bias[row] : bvc);
                Cb[(size_t)row * N + col] = (__bf16)v;
            }
        }
    }
}

__global__ __launch_bounds__(256)
void gemm_kv(const __bf16* __restrict__ kb, const __bf16* __restrict__ wkb,
             const float* __restrict__ bK, __bf16* __restrict__ kp,
             const __bf16* __restrict__ wvb, const __bf16* __restrict__ vb,
             const float* __restrict__ bV, __bf16* __restrict__ vpT) {
    __shared__ __bf16 As[2 * 128 * 32];
    __shared__ __bf16 Bs[2 * 128 * 32];
    const int bid = blockIdx.x;
    const int swz = (bid & 7) * 32 + (bid >> 3);
    if (swz < 128) {
        int bx = swz & 31, by = swz >> 5;
        gemm_tile(kb, wkb, bK, kp, 512, 2048, bx * 128, by * 128, 0, As, Bs);
    } else {
        int s2 = swz - 128;
        int bx = s2 & 3, by = s2 >> 2;
        gemm_tile(wvb, vb, bV, vpT, 4096, 2048, bx * 128, by * 128, 1, As, Bs);
    }
}

// ---------------------------------------------------------------------------
// Flash attention (R5 structure + staggered K/V walk).
// XCD-exact (b,grp) placement: xcd = bid&7. Per-XCD blocks START at different
// tiles (t0 = slot&31) so the 64 blocks sharing one 1 MB K/V set never read
// the same 32 KB tile in the same cycle window (spreads L2 channel load).
// Online softmax is order-invariant, so any tile permutation is exact.
// ---------------------------------------------------------------------------
__global__ __launch_bounds__(256)
void attn_kernel(const __bf16* __restrict__ Qw, const __bf16* __restrict__ Kw,
                 const __bf16* __restrict__ VTw, __bf16* __restrict__ Ow) {
    constexpr int S = 2048, DQ = 2048, DKV = 512, TOK = 4096;
    constexpr int nt = S / 64;
    const int bid = blockIdx.x;
    const int xcd = bid & 7, slot = bid >> 3;
    const int b = xcd >> 2, grp = xcd & 3;
    const int head = grp * 4 + (slot & 3);
    const int qblk = slot >> 2;
    const int t0 = slot & (nt - 1);          // stagger: per-block start tile
    const __bf16* Q   = Qw + (size_t)b * S * DQ + head * 128;
    const __bf16* Kp  = Kw + (size_t)b * S * DKV + grp * 128;
    const __bf16* VTp = VTw + (size_t)(grp * 128) * TOK + (size_t)b * S;
    __bf16* Op = Ow + (size_t)b * S * DQ + head * 128;

    __shared__ __bf16 Ks[2][64 * 128];
    __shared__ __bf16 Vs[2][128 * 64];

    const int tid = threadIdx.x, wid = tid >> 6, lane = tid & 63;
    const int ql = lane & 31, hi = lane >> 5;
    const int qrow = qblk * 128 + wid * 32 + ql;

    bf16x8 qf[8];
#pragma unroll
    for (int ks = 0; ks < 8; ++ks)
        qf[ks] = *(const bf16x8*)(Q + (size_t)qrow * DQ + ks * 16 + hi * 8);

    f32x16 o[4];
#pragma unroll
    for (int d = 0; d < 4; ++d)
#pragma unroll
        for (int r = 0; r < 16; ++r) o[d][r] = 0.f;
    float mprev = -1e30f, lsum = 0.f;
    constexpr float kexp = 0.08838834764831845f * 1.4426950408889634f;
    constexpr float THR = 8.0f / kexp;

    auto stage = [&](int buf, int t) {
#pragma unroll
        for (int i = 0; i < 4; ++i) {
            int ci = i * 256 + tid;
            int key = ci >> 4, ccl = ci & 15, ccg = ccl ^ (key & 15);
            GLD16(Kp + (size_t)(t * 64 + key) * DKV + ccg * 8, &Ks[buf][ci * 8]);
        }
#pragma unroll
        for (int i = 0; i < 4; ++i) {
            int ci = i * 256 + tid;
            int dh = ci >> 3, cl = ci & 7, cg = cl ^ ((dh ^ (dh >> 3)) & 7);
            GLD16(VTp + (size_t)dh * TOK + t * 64 + cg * 8, &Vs[buf][ci * 8]);
        }
    };

    stage(0, t0);
    __syncthreads();

    int cur = 0;
    for (int i = 0; i < nt; ++i) {
        if (i + 1 < nt) stage(cur ^ 1, (t0 + i + 1) & (nt - 1));

        f32x16 sc[2];
        __builtin_amdgcn_s_setprio(1);
#pragma unroll
        for (int kt = 0; kt < 2; ++kt) {
#pragma unroll
            for (int r = 0; r < 16; ++r) sc[kt][r] = 0.f;
#pragma unroll
            for (int ks = 0; ks < 8; ++ks) {
                int key = kt * 32 + ql;
                int chl = (ks * 2 + hi) ^ (key & 15);
                bf16x8 kf = *(const bf16x8*)&Ks[cur][key * 128 + chl * 8];
                sc[kt] = __builtin_amdgcn_mfma_f32_32x32x16_bf16(kf, qf[ks], sc[kt], 0, 0, 0);
            }
        }
        __builtin_amdgcn_s_setprio(0);

        float mo = sc[0][0];
#pragma unroll
        for (int r = 1; r < 16; ++r) mo = fmaxf(mo, sc[0][r]);
#pragma unroll
        for (int r = 0; r < 16; ++r) mo = fmaxf(mo, sc[1][r]);
        mo = fmaxf(mo, __shfl_xor(mo, 32, 64));
        if (!__all(mo - mprev <= THR)) {          // T13 defer-max
            float mn = fmaxf(mprev, mo);
            float ef = EXP2F((mprev - mn) * kexp);
            lsum *= ef;
#pragma unroll
            for (int d = 0; d < 4; ++d)
#pragma unroll
                for (int r = 0; r < 16; ++r) o[d][r] *= ef;
            mprev = mn;
        }
        float mnk = mprev * kexp;
        float rs = 0.f;
#pragma unroll
        for (int kt = 0; kt < 2; ++kt)
#pragma unroll
            for (int r = 0; r < 16; ++r) {
                float p = EXP2F(__builtin_fmaf(sc[kt][r], kexp, -mnk));
                sc[kt][r] = p;
                rs += p;
            }
        rs += __shfl_xor(rs, 32, 64);
        lsum += rs;

        unsigned pk[2][4][2];
#pragma unroll
        for (int kt = 0; kt < 2; ++kt)
#pragma unroll
            for (int rg = 0; rg < 4; ++rg) {
                pk[kt][rg][0] = pack2bf(sc[kt][rg * 4 + 0], sc[kt][rg * 4 + 1]);
                pk[kt][rg][1] = pack2bf(sc[kt][rg * 4 + 2], sc[kt][rg * 4 + 3]);
            }

        __builtin_amdgcn_s_setprio(1);
#pragma unroll
        for (int ks = 0; ks < 4; ++ks) {
            const int kt = ks >> 1, e = ks & 1;
            unsigned a0 = pk[kt][2 * e][0], b0 = pk[kt][2 * e + 1][0];
            unsigned a1 = pk[kt][2 * e][1], b1 = pk[kt][2 * e + 1][1];
            PLSWAP(a0, b0);
            PLSWAP(a1, b1);
            u32x4 fw = {a0, a1, b0, b1};
            bf16x8 pf = __builtin_bit_cast(bf16x8, fw);
#pragma unroll
            for (int dht = 0; dht < 4; ++dht) {
                int dh = dht * 32 + ql;
                int chl = (ks * 2 + hi) ^ ((dh ^ (dh >> 3)) & 7);
                bf16x8 vf = *(const bf16x8*)&Vs[cur][dh * 64 + chl * 8];
                o[dht] = __builtin_amdgcn_mfma_f32_32x32x16_bf16(vf, pf, o[dht], 0, 0, 0);
            }
        }
        __builtin_amdgcn_s_setprio(0);
        __syncthreads();
        cur ^= 1;
    }

    float inv = 1.0f / lsum;
#pragma unroll
    for (int dht = 0; dht < 4; ++dht)
#pragma unroll
        for (int rg = 0; rg < 4; ++rg) {
            bf16x4 wv;
#pragma unroll
            for (int j = 0; j < 4; ++j) wv[j] = (__bf16)(o[dht][rg * 4 + j] * inv);
            int dh0 = dht * 32 + rg * 8 + hi * 4;
            *(bf16x4*)(Op + (size_t)qrow * DQ + dh0) = wv;
        }
}

// ---------------------------------------------------------------------------
extern "C" void kernel_launch(void* const* d_in, const int* in_sizes, int n_in,
                              void* d_out, int out_size, void* d_ws, size_t ws_size,
                              hipStream_t stream) {
    (void)in_sizes; (void)n_in; (void)out_size; (void)ws_size;
    const float* query = (const float*)d_in[0];
    const float* key   = (const float*)d_in[1];
    const float* value = (const float*)d_in[2];
    const float* WQ = (const float*)d_in[3];
    const float* bQ = (const float*)d_in[4];
    const float* WK = (const float*)d_in[5];
    const float* bK = (const float*)d_in[6];
    const float* WV = (const float*)d_in[7];
    const float* bV = (const float*)d_in[8];
    const float* WO = (const float*)d_in[9];
    const float* bO = (const float*)d_in[10];
    float* out = (float*)d_out;

    __bf16* w = (__bf16*)d_ws;
    __bf16* qb  = w; w += (size_t)4096 * 2048;
    __bf16* kb  = w; w += (size_t)4096 * 2048;
    __bf16* vb  = w; w += (size_t)4096 * 2048;
    __bf16* wqb = w; w += (size_t)2048 * 2048;
    __bf16* wkb = w; w += (size_t)512 * 2048;
    __bf16* wvb = w; w += (size_t)512 * 2048;
    __bf16* wob = w; w += (size_t)2048 * 2048;
    __bf16* qp  = w; w += (size_t)4096 * 2048;
    __bf16* kp  = w; w += (size_t)4096 * 512;
    __bf16* vpT = w; w += (size_t)512 * 4096;
    __bf16* ao  = w; w += (size_t)4096 * 2048;

    F2BArgs fa;
    fa.src[0] = query; fa.dst[0] = qb;
    fa.src[1] = key;   fa.dst[1] = kb;
    fa.src[2] = value; fa.dst[2] = vb;
    fa.src[3] = WQ;    fa.dst[3] = wqb;
    fa.src[4] = WK;    fa.dst[4] = wkb;
    fa.src[5] = WV;    fa.dst[5] = wvb;
    fa.src[6] = WO;    fa.dst[6] = wob;
    const long n8s[7] = {1048576, 1048576, 1048576, 524288, 131072, 131072, 524288};
    long acc = 0;
    for (int i = 0; i < 7; ++i) { fa.beg[i] = acc; acc += n8s[i]; }
    fa.beg[7] = acc;
    f2b_multi<<<2048, 256, 0, stream>>>(fa);

    gemm256<0><<<256, 512, 0, stream>>>(qb, wqb, bQ, nullptr, qp, 4096, 2048, 2048, 16);
    gemm_kv<<<256, 256, 0, stream>>>(kb, wkb, bK, kp, wvb, vb, bV, vpT);

    attn_kernel<<<512, 256, 0, stream>>>(qp, kp, vpT, ao);

    gemm256<1><<<256, 512, 0, stream>>>(ao, wob, bO, out, nullptr, 4096, 2048, 2048, 16);
}

// Round 9
// 262.083 us; speedup vs baseline: 2.3337x; 1.0351x over previous
//
#include <hip/hip_runtime.h>
#include <cstdint>
#include <cstddef>

// ---------------------------------------------------------------------------
// Fused GQA MHA: B=2 S=2048 D=2048, G=4 HPG=4 DH=128 (16 heads)
// fused fp32->bf16 | gemm256 (Q proj) + gemm_kv (K, V^T) | flash attn | O proj
// ---------------------------------------------------------------------------

typedef __attribute__((ext_vector_type(8)))  __bf16 bf16x8;
typedef __attribute__((ext_vector_type(4)))  __bf16 bf16x4;
typedef __attribute__((ext_vector_type(4)))  float  f32x4;
typedef __attribute__((ext_vector_type(16))) float  f32x16;
typedef __attribute__((ext_vector_type(4)))  unsigned int u32x4;

#define GLD16(gp, lp) __builtin_amdgcn_global_load_lds(                         \
    (__attribute__((address_space(1))) void*)(size_t)(gp),                     \
    (__attribute__((address_space(3))) void*)(lp), 16, 0, 0)

#define PLSWAP(a, b) asm volatile("v_permlane32_swap_b32 %0, %1" : "+v"(a), "+v"(b))
#define EXP2F(x) __builtin_amdgcn_exp2f(x)

static __device__ __forceinline__ unsigned pack2bf(float a, float b) {
    unsigned short ua = __builtin_bit_cast(unsigned short, (__bf16)a);
    unsigned short ub = __builtin_bit_cast(unsigned short, (__bf16)b);
    return (unsigned)ua | ((unsigned)ub << 16);
}

// ---------------------------------------------------------------------------
// Fused fp32->bf16 for all 7 tensors in one launch
// ---------------------------------------------------------------------------
struct F2BArgs {
    const float* src[7];
    __bf16* dst[7];
    long beg[8];
};
__global__ void f2b_multi(F2BArgs a) {
    const long total = a.beg[7];
    const long stride = (long)gridDim.x * blockDim.x;
    for (long i = (long)blockIdx.x * blockDim.x + threadIdx.x; i < total; i += stride) {
        int s = 0;
#pragma unroll
        for (int j = 1; j < 7; ++j) s += (i >= a.beg[j]);
        long off = i - a.beg[s];
        const float4* p = (const float4*)(a.src[s] + off * 8);
        float4 x = p[0], y = p[1];
        bf16x8 r;
        r[0] = (__bf16)x.x; r[1] = (__bf16)x.y; r[2] = (__bf16)x.z; r[3] = (__bf16)x.w;
        r[4] = (__bf16)y.x; r[5] = (__bf16)y.y; r[6] = (__bf16)y.z; r[7] = (__bf16)y.w;
        *(bf16x8*)(a.dst[s] + off * 8) = r;
    }
}

// ---------------------------------------------------------------------------
// gemm256: BM=256 BN=128 BK=64, 8 waves, triple-buffered, counted vmcnt(6)
// (unchanged — verified R6)
// ---------------------------------------------------------------------------
template <int OUTF32>
__global__ __launch_bounds__(512)
void gemm256(const __bf16* __restrict__ A, const __bf16* __restrict__ Bm,
             const float* __restrict__ bias, float* __restrict__ Cf,
             __bf16* __restrict__ Cb, int M, int N, int K, int nbx) {
    __shared__ __bf16 As[3][256 * 64];
    __shared__ __bf16 Bs[3][128 * 64];
    const int tid = threadIdx.x, lane = tid & 63, wid = tid >> 6;
    const int g = lane >> 4, c = lane & 15;
    const int wr = wid >> 1, wc = wid & 1;
    const int cpx = gridDim.x >> 3;
    const int swz = ((int)blockIdx.x & 7) * cpx + ((int)blockIdx.x >> 3);
    const int bx = swz % nbx, by = swz / nbx;
    const int m0 = by * 256, n0 = bx * 128;
    const int nkt = K >> 6;

    const f32x4 z = {0.f, 0.f, 0.f, 0.f};
    f32x4 acc[4][4];
#pragma unroll
    for (int i = 0; i < 4; ++i)
#pragma unroll
        for (int j = 0; j < 4; ++j) acc[i][j] = z;

    auto stageA = [&](int b, int kt, int h) {
        if (kt >= nkt) return;
        const __bf16* src = A + (size_t)m0 * K + (size_t)kt * 64;
#pragma unroll
        for (int i = 0; i < 2; ++i) {
            int ci = h * 1024 + i * 512 + tid;
            int row = ci >> 3, chg = (ci & 7) ^ (row & 7);
            GLD16(src + (size_t)row * K + chg * 8, &As[b][ci * 8]);
        }
    };
    auto stageB = [&](int b, int kt) {
        if (kt >= nkt) return;
        const __bf16* src = Bm + (size_t)n0 * K + (size_t)kt * 64;
#pragma unroll
        for (int i = 0; i < 2; ++i) {
            int ci = i * 512 + tid;
            int row = ci >> 3, chg = (ci & 7) ^ (row & 7);
            GLD16(src + (size_t)row * K + chg * 8, &Bs[b][ci * 8]);
        }
    };

    stageA(0, 0, 0); stageA(0, 0, 1); stageB(0, 0);
    stageA(1, 1, 0); stageA(1, 1, 1); stageB(1, 1);
    asm volatile("s_waitcnt vmcnt(6)" ::: "memory");
    __builtin_amdgcn_sched_barrier(0);
    __builtin_amdgcn_s_barrier();

    int bd = 0;
    for (int kt = 0; kt < nkt; ++kt) {
        const int bs = (bd >= 1) ? bd - 1 : 2;
        bf16x8 af[4], bfr[4];
#pragma unroll
        for (int ph = 0; ph < 2; ++ph) {
#pragma unroll
            for (int mi = 0; mi < 4; ++mi) {
                int row = wr * 64 + mi * 16 + c;
                int ch = (ph * 4 + g) ^ (c & 7);
                af[mi] = *(const bf16x8*)&As[bd][row * 64 + ch * 8];
            }
#pragma unroll
            for (int ni = 0; ni < 4; ++ni) {
                int row = wc * 64 + ni * 16 + c;
                int ch = (ph * 4 + g) ^ (c & 7);
                bfr[ni] = *(const bf16x8*)&Bs[bd][row * 64 + ch * 8];
            }
            if (ph == 0) {
                stageA(bs, kt + 2, 0);
            } else {
                stageA(bs, kt + 2, 1);
                stageB(bs, kt + 2);
            }
            __builtin_amdgcn_s_barrier();
            asm volatile("s_waitcnt lgkmcnt(0)" ::: "memory");
            __builtin_amdgcn_sched_barrier(0);
            __builtin_amdgcn_s_setprio(1);
#pragma unroll
            for (int mi = 0; mi < 4; ++mi)
#pragma unroll
                for (int ni = 0; ni < 4; ++ni)
                    acc[mi][ni] = __builtin_amdgcn_mfma_f32_16x16x32_bf16(
                        af[mi], bfr[ni], acc[mi][ni], 0, 0, 0);
            __builtin_amdgcn_s_setprio(0);
            if (ph == 1) {
                if (kt >= nkt - 2) asm volatile("s_waitcnt vmcnt(0)" ::: "memory");
                else               asm volatile("s_waitcnt vmcnt(6)" ::: "memory");
                __builtin_amdgcn_sched_barrier(0);
            }
            __builtin_amdgcn_s_barrier();
        }
        bd = (bd >= 2) ? 0 : bd + 1;
    }

#pragma unroll
    for (int mi = 0; mi < 4; ++mi) {
#pragma unroll
        for (int ni = 0; ni < 4; ++ni) {
            int col = n0 + wc * 64 + ni * 16 + c;
            float bvc = bias[col];
#pragma unroll
            for (int r = 0; r < 4; ++r) {
                int row = m0 + wr * 64 + mi * 16 + g * 4 + r;
                float v = acc[mi][ni][r] + bvc;
                if (OUTF32) Cf[(size_t)row * N + col] = v;
                else        Cb[(size_t)row * N + col] = (__bf16)v;
            }
        }
    }
}

// ---------------------------------------------------------------------------
// m97-structure tile body for the small K/V projections (unchanged)
// ---------------------------------------------------------------------------
static __device__ __forceinline__
void gemm_tile(const __bf16* __restrict__ A, const __bf16* __restrict__ Bm,
               const float* __restrict__ bias,
               __bf16* __restrict__ Cb, int N, int K, int m0, int n0, int biasrow,
               __bf16* As, __bf16* Bs) {
    const int tid = threadIdx.x;
    const int lane = tid & 63, wid = tid >> 6;
    const int g = lane >> 4, c = lane & 15;
    const int wr = wid >> 1, wc = wid & 1;

    const f32x4 z = {0.f, 0.f, 0.f, 0.f};
    f32x4 acc[4][4];
#pragma unroll
    for (int i = 0; i < 4; ++i)
#pragma unroll
        for (int j = 0; j < 4; ++j) acc[i][j] = z;

    const int nk = K >> 5;
#pragma unroll
    for (int i = 0; i < 2; ++i) {
        int ci = i * 256 + tid, row = ci >> 2, kc = (ci & 3) * 8;
        GLD16(A + (size_t)(m0 + row) * K + kc, As + ci * 8);
        GLD16(Bm + (size_t)(n0 + row) * K + kc, Bs + ci * 8);
    }
    __syncthreads();

    int cur = 0;
    for (int t = 0; t < nk; ++t) {
        if (t + 1 < nk) {
            int koff = (t + 1) * 32;
            int nb = (cur ^ 1) * 4096;
#pragma unroll
            for (int i = 0; i < 2; ++i) {
                int ci = i * 256 + tid, row = ci >> 2, kc = (ci & 3) * 8;
                GLD16(A + (size_t)(m0 + row) * K + koff + kc, As + nb + ci * 8);
                GLD16(Bm + (size_t)(n0 + row) * K + koff + kc, Bs + nb + ci * 8);
            }
        }
        int cb = cur * 4096;
        bf16x8 af[4], bfv[4];
#pragma unroll
        for (int im = 0; im < 4; ++im)
            af[im] = *(const bf16x8*)&As[cb + (wr * 64 + im * 16 + c) * 32 + g * 8];
#pragma unroll
        for (int in = 0; in < 4; ++in)
            bfv[in] = *(const bf16x8*)&Bs[cb + (wc * 64 + in * 16 + c) * 32 + g * 8];
        __builtin_amdgcn_s_setprio(1);
#pragma unroll
        for (int im = 0; im < 4; ++im)
#pragma unroll
            for (int in = 0; in < 4; ++in)
                acc[im][in] = __builtin_amdgcn_mfma_f32_16x16x32_bf16(
                    af[im], bfv[in], acc[im][in], 0, 0, 0);
        __builtin_amdgcn_s_setprio(0);
        __syncthreads();
        cur ^= 1;
    }

#pragma unroll
    for (int im = 0; im < 4; ++im) {
#pragma unroll
        for (int in = 0; in < 4; ++in) {
            int col = n0 + wc * 64 + in * 16 + c;
            float bvc = biasrow ? 0.f : bias[col];
#pragma unroll
            for (int r = 0; r < 4; ++r) {
                int row = m0 + wr * 64 + im * 16 + g * 4 + r;
                float v = acc[im][in][r] + (biasrow ? bias[row] : bvc);
                Cb[(size_t)row * N + col] = (__bf16)v;
            }
        }
    }
}

__global__ __launch_bounds__(256)
void gemm_kv(const __bf16* __restrict__ kb, const __bf16* __restrict__ wkb,
             const float* __restrict__ bK, __bf16* __restrict__ kp,
             const __bf16* __restrict__ wvb, const __bf16* __restrict__ vb,
             const float* __restrict__ bV, __bf16* __restrict__ vpT) {
    __shared__ __bf16 As[2 * 128 * 32];
    __shared__ __bf16 Bs[2 * 128 * 32];
    const int bid = blockIdx.x;
    const int swz = (bid & 7) * 32 + (bid >> 3);
    if (swz < 128) {
        int bx = swz & 31, by = swz >> 5;
        gemm_tile(kb, wkb, bK, kp, 512, 2048, bx * 128, by * 128, 0, As, Bs);
    } else {
        int s2 = swz - 128;
        int bx = s2 & 3, by = s2 >> 2;
        gemm_tile(wvb, vb, bV, vpT, 4096, 2048, bx * 128, by * 128, 1, As, Bs);
    }
}

// ---------------------------------------------------------------------------
// Flash attention: 32x32x16 swapped-operand, XCD-exact placement, staggered
// start, and NOW T3/T4: KVBLK=32, triple-buffered K/V^T, pipeline depth 2,
// counted vmcnt(4) + raw s_barrier (never vmcnt(0) mid-loop).
// K  tile [32 keys][128 dh], chunk ^= key&15
// V^T tile [128 dh][32 keys], chunk ^= (dh>>1)&3
// ---------------------------------------------------------------------------
__global__ __launch_bounds__(256)
void attn_kernel(const __bf16* __restrict__ Qw, const __bf16* __restrict__ Kw,
                 const __bf16* __restrict__ VTw, __bf16* __restrict__ Ow) {
    constexpr int S = 2048, DQ = 2048, DKV = 512, TOK = 4096;
    constexpr int nt = S / 32;                 // 64 tiles of 32 keys
    const int bid = blockIdx.x;
    const int xcd = bid & 7, slot = bid >> 3;
    const int b = xcd >> 2, grp = xcd & 3;
    const int head = grp * 4 + (slot & 3);
    const int qblk = slot >> 2;
    const int t0 = slot & (nt - 1);            // stagger start tile
    const __bf16* Q   = Qw + (size_t)b * S * DQ + head * 128;
    const __bf16* Kp  = Kw + (size_t)b * S * DKV + grp * 128;
    const __bf16* VTp = VTw + (size_t)(grp * 128) * TOK + (size_t)b * S;
    __bf16* Op = Ow + (size_t)b * S * DQ + head * 128;

    __shared__ __bf16 Ks[3][32 * 128];   // 24 KB
    __shared__ __bf16 Vs[3][128 * 32];   // 24 KB

    const int tid = threadIdx.x, wid = tid >> 6, lane = tid & 63;
    const int ql = lane & 31, hi = lane >> 5;
    const int qrow = qblk * 128 + wid * 32 + ql;

    bf16x8 qf[8];
#pragma unroll
    for (int ks = 0; ks < 8; ++ks)
        qf[ks] = *(const bf16x8*)(Q + (size_t)qrow * DQ + ks * 16 + hi * 8);

    f32x16 o[4];
#pragma unroll
    for (int d = 0; d < 4; ++d)
#pragma unroll
        for (int r = 0; r < 16; ++r) o[d][r] = 0.f;
    float mprev = -1e30f, lsum = 0.f;
    constexpr float kexp = 0.08838834764831845f * 1.4426950408889634f;
    constexpr float THR = 8.0f / kexp;

    // stage one 32-key tile: K 8KB (2 GLD16) + V^T 8KB (2 GLD16)
    auto stage = [&](int buf, int t) {
#pragma unroll
        for (int i = 0; i < 2; ++i) {          // K [key][chunk^key&15]
            int ci = i * 256 + tid;            // [0,512)
            int key = ci >> 4, ccl = ci & 15, ccg = ccl ^ (key & 15);
            GLD16(Kp + (size_t)(t * 32 + key) * DKV + ccg * 8, &Ks[buf][ci * 8]);
        }
#pragma unroll
        for (int i = 0; i < 2; ++i) {          // V^T [dh][chunk^((dh>>1)&3)]
            int ci = i * 256 + tid;            // [0,512)
            int dh = ci >> 2, cl = ci & 3, cg = cl ^ ((dh >> 1) & 3);
            GLD16(VTp + (size_t)dh * TOK + t * 32 + cg * 8, &Vs[buf][ci * 8]);
        }
    };

    // prologue: tiles 0,1 in flight; wait tile 0 landed (tile 1 stays in flight)
    stage(0, t0);
    stage(1, (t0 + 1) & (nt - 1));
    asm volatile("s_waitcnt vmcnt(4)" ::: "memory");
    asm volatile("s_barrier" ::: "memory");

    int bc = 0;
    for (int i = 0; i < nt; ++i) {
        const int bs = (bc >= 1) ? bc - 1 : 2;           // buffer for tile i+2
        if (i + 2 < nt) stage(bs, (t0 + i + 2) & (nt - 1));

        // ---- QK^T: sc = K(32x128) x Q^T(128x32)
        f32x16 sc;
#pragma unroll
        for (int r = 0; r < 16; ++r) sc[r] = 0.f;
        __builtin_amdgcn_s_setprio(1);
#pragma unroll
        for (int ks = 0; ks < 8; ++ks) {
            int chl = (ks * 2 + hi) ^ (ql & 15);
            bf16x8 kf = *(const bf16x8*)&Ks[bc][ql * 128 + chl * 8];
            sc = __builtin_amdgcn_mfma_f32_32x32x16_bf16(kf, qf[ks], sc, 0, 0, 0);
        }
        __builtin_amdgcn_s_setprio(0);

        // ---- online softmax (lane-local q = ql; 32 keys split across hi)
        float mo = sc[0];
#pragma unroll
        for (int r = 1; r < 16; ++r) mo = fmaxf(mo, sc[r]);
        mo = fmaxf(mo, __shfl_xor(mo, 32, 64));
        if (!__all(mo - mprev <= THR)) {                 // T13 defer-max
            float mn = fmaxf(mprev, mo);
            float ef = EXP2F((mprev - mn) * kexp);
            lsum *= ef;
#pragma unroll
            for (int d = 0; d < 4; ++d)
#pragma unroll
                for (int r = 0; r < 16; ++r) o[d][r] *= ef;
            mprev = mn;
        }
        float mnk = mprev * kexp;
        float rs = 0.f;
#pragma unroll
        for (int r = 0; r < 16; ++r) {
            float p = EXP2F(__builtin_fmaf(sc[r], kexp, -mnk));
            sc[r] = p;
            rs += p;
        }
        rs += __shfl_xor(rs, 32, 64);
        lsum += rs;

        // ---- pack P: pk[rg] covers keys {0..3}+8rg+4hi
        unsigned pk[4][2];
#pragma unroll
        for (int rg = 0; rg < 4; ++rg) {
            pk[rg][0] = pack2bf(sc[rg * 4 + 0], sc[rg * 4 + 1]);
            pk[rg][1] = pack2bf(sc[rg * 4 + 2], sc[rg * 4 + 3]);
        }

        // ---- PV: o[dht] += V^T(32x16) x P(16x32) over 2 key-steps
        __builtin_amdgcn_s_setprio(1);
#pragma unroll
        for (int e = 0; e < 2; ++e) {
            unsigned a0 = pk[2 * e][0], b0 = pk[2 * e + 1][0];
            unsigned a1 = pk[2 * e][1], b1 = pk[2 * e + 1][1];
            PLSWAP(a0, b0);
            PLSWAP(a1, b1);
            u32x4 fw = {a0, a1, b0, b1};
            bf16x8 pf = __builtin_bit_cast(bf16x8, fw);
#pragma unroll
            for (int dht = 0; dht < 4; ++dht) {
                int dh = dht * 32 + ql;
                int chl = (e * 2 + hi) ^ ((dh >> 1) & 3);
                bf16x8 vf = *(const bf16x8*)&Vs[bc][dh * 32 + chl * 8];
                o[dht] = __builtin_amdgcn_mfma_f32_32x32x16_bf16(vf, pf, o[dht], 0, 0, 0);
            }
        }
        __builtin_amdgcn_s_setprio(0);

        // ---- counted wait: tile i+1 landed (its 4 loads are the oldest);
        //      tile i+2's 4 loads stay in flight. Tail: full drain.
        if (i + 2 < nt) asm volatile("s_waitcnt vmcnt(4)" ::: "memory");
        else            asm volatile("s_waitcnt vmcnt(0)" ::: "memory");
        asm volatile("s_barrier" ::: "memory");
        bc = (bc >= 2) ? 0 : bc + 1;
    }

    // ---- epilogue: dh = dht*32 + 8*(r>>2) + 4*hi + (r&3)
    float inv = 1.0f / lsum;
#pragma unroll
    for (int dht = 0; dht < 4; ++dht)
#pragma unroll
        for (int rg = 0; rg < 4; ++rg) {
            bf16x4 wv;
#pragma unroll
            for (int j = 0; j < 4; ++j) wv[j] = (__bf16)(o[dht][rg * 4 + j] * inv);
            int dh0 = dht * 32 + rg * 8 + hi * 4;
            *(bf16x4*)(Op + (size_t)qrow * DQ + dh0) = wv;
        }
}

// ---------------------------------------------------------------------------
extern "C" void kernel_launch(void* const* d_in, const int* in_sizes, int n_in,
                              void* d_out, int out_size, void* d_ws, size_t ws_size,
                              hipStream_t stream) {
    (void)in_sizes; (void)n_in; (void)out_size; (void)ws_size;
    const float* query = (const float*)d_in[0];
    const float* key   = (const float*)d_in[1];
    const float* value = (const float*)d_in[2];
    const float* WQ = (const float*)d_in[3];
    const float* bQ = (const float*)d_in[4];
    const float* WK = (const float*)d_in[5];
    const float* bK = (const float*)d_in[6];
    const float* WV = (const float*)d_in[7];
    const float* bV = (const float*)d_in[8];
    const float* WO = (const float*)d_in[9];
    const float* bO = (const float*)d_in[10];
    float* out = (float*)d_out;

    __bf16* w = (__bf16*)d_ws;
    __bf16* qb  = w; w += (size_t)4096 * 2048;
    __bf16* kb  = w; w += (size_t)4096 * 2048;
    __bf16* vb  = w; w += (size_t)4096 * 2048;
    __bf16* wqb = w; w += (size_t)2048 * 2048;
    __bf16* wkb = w; w += (size_t)512 * 2048;
    __bf16* wvb = w; w += (size_t)512 * 2048;
    __bf16* wob = w; w += (size_t)2048 * 2048;
    __bf16* qp  = w; w += (size_t)4096 * 2048;
    __bf16* kp  = w; w += (size_t)4096 * 512;
    __bf16* vpT = w; w += (size_t)512 * 4096;
    __bf16* ao  = w; w += (size_t)4096 * 2048;

    F2BArgs fa;
    fa.src[0] = query; fa.dst[0] = qb;
    fa.src[1] = key;   fa.dst[1] = kb;
    fa.src[2] = value; fa.dst[2] = vb;
    fa.src[3] = WQ;    fa.dst[3] = wqb;
    fa.src[4] = WK;    fa.dst[4] = wkb;
    fa.src[5] = WV;    fa.dst[5] = wvb;
    fa.src[6] = WO;    fa.dst[6] = wob;
    const long n8s[7] = {1048576, 1048576, 1048576, 524288, 131072, 131072, 524288};
    long acc = 0;
    for (int i = 0; i < 7; ++i) { fa.beg[i] = acc; acc += n8s[i]; }
    fa.beg[7] = acc;
    f2b_multi<<<2048, 256, 0, stream>>>(fa);

    gemm256<0><<<256, 512, 0, stream>>>(qb, wqb, bQ, nullptr, qp, 4096, 2048, 2048, 16);
    gemm_kv<<<256, 256, 0, stream>>>(kb, wkb, bK, kp, wvb, vb, bV, vpT);

    attn_kernel<<<512, 256, 0, stream>>>(qp, kp, vpT, ao);

    gemm256<1><<<256, 512, 0, stream>>>(ao, wob, bO, out, nullptr, 4096, 2048, 2048, 16);
}